// Round 2
// baseline (271.869 us; speedup 1.0000x reference)
//
#include <hip/hip_runtime.h>
#include <hip/hip_bf16.h>

// GCN encoder, N=50000 nodes, E=800000 edges, 128 -> 96 (relu) -> sum-pooled 64+64.
// Key identity: sum-pooled second layer == (sum_u c[u]*h[u]) @ W + N*b,
//   c[u] = dinv[u]*(dinv[u] + sum_{edges u->d} dinv[d]).
// Layer 1 with g[u] = h1[u]*dinv[u]:
//   h[d] = relu( dinv[d] * ( sum_{e->d} g[src] + g[d] ) + b1 )   // g[d] term = self-loop

#define NTHREADS 256

__device__ inline void fma4(float4& c, float a, const float4& b) {
    c.x = fmaf(a, b.x, c.x); c.y = fmaf(a, b.y, c.y);
    c.z = fmaf(a, b.z, c.z); c.w = fmaf(a, b.w, c.w);
}

// ---- 1. in-degree count (excluding self-loop, added analytically) ----
__global__ void k_deg(const int* __restrict__ dst, int* __restrict__ deg, int E) {
    int e = blockIdx.x * NTHREADS + threadIdx.x;
    if (e < E) atomicAdd(&deg[dst[e]], 1);
}

// ---- 2. dinv = (deg+1)^-0.5 ----
__global__ void k_dinv(const int* __restrict__ deg, float* __restrict__ dinv, int n) {
    int u = blockIdx.x * NTHREADS + threadIdx.x;
    if (u < n) dinv[u] = rsqrtf((float)(deg[u] + 1));
}

// ---- 3. exclusive scan of deg -> rowptr (single block, 8 elems/thread/pass) ----
#define SCAN_T 1024
#define SCAN_V 8
__global__ void k_scan(const int* __restrict__ deg, int* __restrict__ rowptr, int n) {
    __shared__ int sh[SCAN_T];
    __shared__ int s_carry;
    int tid = threadIdx.x;
    if (tid == 0) s_carry = 0;
    __syncthreads();
    for (int base = 0; base < n; base += SCAN_T * SCAN_V) {
        int vals[SCAN_V];
        int idx0 = base + tid * SCAN_V;
        int local = 0;
        #pragma unroll
        for (int i = 0; i < SCAN_V; ++i) {
            int ix = idx0 + i;
            int v = (ix < n) ? deg[ix] : 0;
            vals[i] = local;         // exclusive within thread
            local += v;
        }
        sh[tid] = local;
        __syncthreads();
        // inclusive scan of sh
        for (int off = 1; off < SCAN_T; off <<= 1) {
            int t = (tid >= off) ? sh[tid - off] : 0;
            __syncthreads();
            sh[tid] += t;
            __syncthreads();
        }
        int texc = ((tid > 0) ? sh[tid - 1] : 0) + s_carry;
        #pragma unroll
        for (int i = 0; i < SCAN_V; ++i) {
            int ix = idx0 + i;
            if (ix < n) rowptr[ix] = texc + vals[i];
        }
        __syncthreads();
        if (tid == 0) s_carry += sh[SCAN_T - 1];
        __syncthreads();
    }
    if (tid == 0) rowptr[n] = s_carry;
}

// ---- 4. fill CSR col list; accumulate r[s] = sum dinv[dst] over out-edges ----
__global__ void k_fill(const int* __restrict__ src, const int* __restrict__ dst,
                       const float* __restrict__ dinv, int* __restrict__ cursor,
                       const int* __restrict__ rowptr, int* __restrict__ col,
                       float* __restrict__ rsum, int E) {
    int e = blockIdx.x * NTHREADS + threadIdx.x;
    if (e >= E) return;
    int s = src[e], d = dst[e];
    int pos = rowptr[d] + atomicAdd(&cursor[d], 1);
    col[pos] = s;
    atomicAdd(&rsum[s], dinv[d]);
}

// ---- 5. g = (x @ W1) * dinv[row]   (M=50000, K=128, Ncols=96) ----
// block 256 = (tx 0..7 col-groups of 12) x (ty 0..31 row-pairs); tile 64 rows.
__launch_bounds__(256)
__global__ void k_gemm(const float* __restrict__ x, const float* __restrict__ W1,
                       const float* __restrict__ dinv, float* __restrict__ g, int n) {
    __shared__ float Ws[128 * 96];
    int tid = threadIdx.x;
    {   // stage W1 (12288 floats = 3072 float4)
        const float4* wsrc = (const float4*)W1;
        float4* wdst = (float4*)Ws;
        #pragma unroll
        for (int i = 0; i < 12; ++i) wdst[tid + 256 * i] = wsrc[tid + 256 * i];
    }
    __syncthreads();

    int tx = tid & 7;         // 8 col groups * 12 cols
    int ty = tid >> 3;        // 32 row pairs
    int r0 = blockIdx.x * 64 + ty * 2;
    int r1 = r0 + 1;
    bool v0 = r0 < n, v1 = r1 < n;
    const float4* x0 = (const float4*)(x + (size_t)(v0 ? r0 : 0) * 128);
    const float4* x1 = (const float4*)(x + (size_t)(v1 ? r1 : 0) * 128);

    float4 acc[2][3];
    #pragma unroll
    for (int i = 0; i < 2; ++i)
        #pragma unroll
        for (int j = 0; j < 3; ++j) acc[i][j] = make_float4(0.f, 0.f, 0.f, 0.f);

    #pragma unroll 4
    for (int k4 = 0; k4 < 32; ++k4) {
        float4 a0 = x0[k4];
        float4 a1 = x1[k4];
        #pragma unroll
        for (int kk = 0; kk < 4; ++kk) {
            const float* wrow = &Ws[(k4 * 4 + kk) * 96 + tx * 12];
            float4 b0 = *(const float4*)(wrow);
            float4 b1 = *(const float4*)(wrow + 4);
            float4 b2 = *(const float4*)(wrow + 8);
            float av0 = (kk == 0) ? a0.x : (kk == 1) ? a0.y : (kk == 2) ? a0.z : a0.w;
            float av1 = (kk == 0) ? a1.x : (kk == 1) ? a1.y : (kk == 2) ? a1.z : a1.w;
            fma4(acc[0][0], av0, b0); fma4(acc[0][1], av0, b1); fma4(acc[0][2], av0, b2);
            fma4(acc[1][0], av1, b0); fma4(acc[1][1], av1, b1); fma4(acc[1][2], av1, b2);
        }
    }

    if (v0) {
        float dv = dinv[r0];
        float4* o = (float4*)(g + (size_t)r0 * 96 + tx * 12);
        float4 t;
        t = acc[0][0]; t.x *= dv; t.y *= dv; t.z *= dv; t.w *= dv; o[0] = t;
        t = acc[0][1]; t.x *= dv; t.y *= dv; t.z *= dv; t.w *= dv; o[1] = t;
        t = acc[0][2]; t.x *= dv; t.y *= dv; t.z *= dv; t.w *= dv; o[2] = t;
    }
    if (v1) {
        float dv = dinv[r1];
        float4* o = (float4*)(g + (size_t)r1 * 96 + tx * 12);
        float4 t;
        t = acc[1][0]; t.x *= dv; t.y *= dv; t.z *= dv; t.w *= dv; o[0] = t;
        t = acc[1][1]; t.x *= dv; t.y *= dv; t.z *= dv; t.w *= dv; o[1] = t;
        t = acc[1][2]; t.x *= dv; t.y *= dv; t.z *= dv; t.w *= dv; o[2] = t;
    }
}

// ---- 6. per-node gather + fused bias/relu/c[d] weight + block partial of v ----
#define AGG_NODES 16
#define AGG_T (AGG_NODES * 24)   // 384 threads = 6 waves
__launch_bounds__(AGG_T)
__global__ void k_agg(const float4* __restrict__ g4, const int* __restrict__ col,
                      const int* __restrict__ rowptr, const float* __restrict__ dinv,
                      const float* __restrict__ rsum, const float* __restrict__ b1,
                      float* __restrict__ v_part, int n) {
    int tid = threadIdx.x;
    int nl = tid / 24;        // node within block
    int ch = tid % 24;        // float4 chunk of 96
    int d = blockIdx.x * AGG_NODES + nl;

    __shared__ float4 sh[AGG_NODES][24];

    float4 contrib = make_float4(0.f, 0.f, 0.f, 0.f);
    if (d < n) {
        float dd = dinv[d];
        int e0 = rowptr[d], e1 = rowptr[d + 1];
        float4 acc = make_float4(0.f, 0.f, 0.f, 0.f);
        for (int e = e0; e < e1; ++e) {
            int s = col[e];                       // broadcast across the 24 lanes
            float4 gv = g4[(size_t)s * 24 + ch];  // coalesced 384B per edge
            acc.x += gv.x; acc.y += gv.y; acc.z += gv.z; acc.w += gv.w;
        }
        float4 gd = g4[(size_t)d * 24 + ch];
        float4 b1c = ((const float4*)b1)[ch];
        // self-loop: h1[d]*dinv[d]^2 == g[d]*dinv[d]  (g already carries one dinv)
        float cd = dd * (dd + rsum[d]);
        float hx = fmaxf(fmaf(dd, acc.x + gd.x, b1c.x), 0.f);
        float hy = fmaxf(fmaf(dd, acc.y + gd.y, b1c.y), 0.f);
        float hz = fmaxf(fmaf(dd, acc.z + gd.z, b1c.z), 0.f);
        float hw = fmaxf(fmaf(dd, acc.w + gd.w, b1c.w), 0.f);
        contrib = make_float4(cd * hx, cd * hy, cd * hz, cd * hw);
    }
    sh[nl][ch] = contrib;
    __syncthreads();
    #pragma unroll
    for (int off = 8; off >= 1; off >>= 1) {
        if (nl < off) {
            float4 a = sh[nl][ch];
            float4 b = sh[nl + off][ch];
            a.x += b.x; a.y += b.y; a.z += b.z; a.w += b.w;
            sh[nl][ch] = a;
        }
        __syncthreads();
    }
    if (tid < 24) {
        ((float4*)(v_part + (size_t)blockIdx.x * 96))[tid] = sh[0][tid];
    }
}

// ---- 7. reduce v_part -> v[96] ----
__global__ void k_vred(const float* __restrict__ vp, float* __restrict__ v, int nb) {
    int j = blockIdx.x;   // 96 blocks
    float s = 0.f;
    for (int i = threadIdx.x; i < nb; i += 256) s += vp[(size_t)i * 96 + j];
    __shared__ float sh[256];
    sh[threadIdx.x] = s;
    __syncthreads();
    for (int off = 128; off; off >>= 1) {
        if (threadIdx.x < off) sh[threadIdx.x] += sh[threadIdx.x + off];
        __syncthreads();
    }
    if (threadIdx.x == 0) v[j] = sh[0];
}

// ---- 8. mu = v@W_mu + N*b_mu ; logvar = v@W_lv + N*b_lv ----
__global__ void k_out(const float* __restrict__ v,
                      const float* __restrict__ Wmu, const float* __restrict__ bmu,
                      const float* __restrict__ Wlv, const float* __restrict__ blv,
                      float* __restrict__ out, float nN) {
    int tid = threadIdx.x;   // 128
    const float* W = (tid < 64) ? Wmu : Wlv;
    const float* b = (tid < 64) ? bmu : blv;
    int j = tid & 63;
    float s = 0.f;
    #pragma unroll
    for (int k = 0; k < 96; ++k) s = fmaf(v[k], W[k * 64 + j], s);
    out[tid] = s + nN * b[j];
}

extern "C" void kernel_launch(void* const* d_in, const int* in_sizes, int n_in,
                              void* d_out, int out_size, void* d_ws, size_t ws_size,
                              hipStream_t stream) {
    const float* x   = (const float*)d_in[0];
    const int*   ei  = (const int*)d_in[1];
    const float* W1  = (const float*)d_in[2];
    const float* b1  = (const float*)d_in[3];
    const float* Wmu = (const float*)d_in[4];
    const float* bmu = (const float*)d_in[5];
    const float* Wlv = (const float*)d_in[6];
    const float* blv = (const float*)d_in[7];
    float* out = (float*)d_out;

    const int N = in_sizes[0] / 128;   // 50000
    const int E = in_sizes[1] / 2;     // 800000
    const int* src = ei;
    const int* dst = ei + E;

    // workspace layout (256B aligned segments)
    size_t off = 0;
    auto alloc = [&](size_t bytes) -> char* {
        off = (off + 255) & ~(size_t)255;
        char* p = (char*)d_ws + off;
        off += bytes;
        return p;
    };
    int*   zero_base = (int*)alloc((size_t)3 * N * 4);  // deg | cursor | rsum
    int*   deg    = zero_base;
    int*   cursor = zero_base + N;
    float* rsum   = (float*)(zero_base + 2 * N);
    int*   rowptr = (int*)alloc((size_t)(N + 1) * 4);
    int*   col    = (int*)alloc((size_t)E * 4);
    float* dinv   = (float*)alloc((size_t)N * 4);
    float* g      = (float*)alloc((size_t)N * 96 * 4);
    const int nAggBlocks = (N + AGG_NODES - 1) / AGG_NODES;   // 3125
    float* v_part = (float*)alloc((size_t)nAggBlocks * 96 * 4);
    float* v      = (float*)alloc(96 * 4);

    hipMemsetAsync(zero_base, 0, (size_t)3 * N * 4, stream);

    const int gE = (E + NTHREADS - 1) / NTHREADS;
    const int gN = (N + NTHREADS - 1) / NTHREADS;

    k_deg<<<gE, NTHREADS, 0, stream>>>(dst, deg, E);
    k_dinv<<<gN, NTHREADS, 0, stream>>>(deg, dinv, N);
    k_scan<<<1, SCAN_T, 0, stream>>>(deg, rowptr, N);
    k_fill<<<gE, NTHREADS, 0, stream>>>(src, dst, dinv, cursor, rowptr, col, rsum, E);
    k_gemm<<<(N + 63) / 64, 256, 0, stream>>>(x, W1, dinv, g, N);
    k_agg<<<nAggBlocks, AGG_T, 0, stream>>>((const float4*)g, col, rowptr, dinv,
                                            rsum, b1, v_part, N);
    k_vred<<<96, 256, 0, stream>>>(v_part, v, nAggBlocks);
    k_out<<<1, 128, 0, stream>>>(v, Wmu, bmu, Wlv, blv, out, (float)N);
}

// Round 3
// 211.362 us; speedup vs baseline: 1.2863x; 1.2863x over previous
//
#include <hip/hip_runtime.h>
#include <hip/hip_bf16.h>

// GCN encoder, N=50000, E=800000, 128 -> 96 (relu) -> sum-pooled 64+64.
// Sum-pooled layer 2: out = (sum_u c[u]*h[u]) @ W + N*b,
//   c[u] = dinv[u]*(dinv[u] + rsum[u]),  rsum[u] = sum_{e: src=u} dinv[dst_e].
// Layer 1 with g[u] = (xW1)[u]*dinv[u]:
//   h[d] = relu( dinv[d]*(sum_{e->d} g[src] + g[d]) + b1 )
// CSR build = 2-level counting sort (64 edge-chunks x 8 node-slices),
// ZERO device-scope atomics (k_fill's 1.6M atomics were 8-12 ops/cyc bound).

#define NTHREADS 256
#define NCHUNK 64
#define NSLICE 8
#define SLICE_MAX 6272   // LDS hist capacity; N <= 8*6272

__device__ inline void fma4(float4& c, float a, const float4& b) {
    c.x = fmaf(a, b.x, c.x); c.y = fmaf(a, b.y, c.y);
    c.z = fmaf(a, b.z, c.z); c.w = fmaf(a, b.w, c.w);
}

// ---- K1: per-(chunk,slice) dst histogram via LDS ----
__launch_bounds__(256)
__global__ void k_count(const int* __restrict__ dst, int* __restrict__ partial,
                        int N, int E, int chunkE, int sliceN) {
    int c = blockIdx.x >> 3, s = blockIdx.x & (NSLICE - 1);
    int nbase = s * sliceN;
    __shared__ int hist[SLICE_MAX];
    for (int j = threadIdx.x; j < sliceN; j += 256) hist[j] = 0;
    __syncthreads();
    int e0 = c * chunkE, e1 = min(e0 + chunkE, E);
    int ne = e1 - e0;
    const int4* d4 = (const int4*)(dst + e0);
    int n4 = ne >> 2;
    for (int i = threadIdx.x; i < n4; i += 256) {
        int4 d = d4[i];
        unsigned q;
        q = (unsigned)(d.x - nbase); if (q < (unsigned)sliceN) atomicAdd(&hist[q], 1);
        q = (unsigned)(d.y - nbase); if (q < (unsigned)sliceN) atomicAdd(&hist[q], 1);
        q = (unsigned)(d.z - nbase); if (q < (unsigned)sliceN) atomicAdd(&hist[q], 1);
        q = (unsigned)(d.w - nbase); if (q < (unsigned)sliceN) atomicAdd(&hist[q], 1);
    }
    if (threadIdx.x < (ne & 3)) {
        int d = dst[e0 + (n4 << 2) + threadIdx.x];
        unsigned q = (unsigned)(d - nbase);
        if (q < (unsigned)sliceN) atomicAdd(&hist[q], 1);
    }
    __syncthreads();
    for (int j = threadIdx.x; j < sliceN; j += 256) {
        int n = nbase + j;
        if (n < N) partial[(size_t)c * N + n] = hist[j];
    }
}

// ---- K2: deg = sum over chunks; dinv = rsqrt(deg+1) ----
__global__ void k_degdinv(const int* __restrict__ partial, int* __restrict__ deg,
                          float* __restrict__ dinv, int N) {
    int n = blockIdx.x * 256 + threadIdx.x;
    if (n >= N) return;
    int s = 0;
    #pragma unroll
    for (int c = 0; c < NCHUNK; ++c) s += partial[(size_t)c * N + n];
    deg[n] = s;
    dinv[n] = rsqrtf((float)(s + 1));
}

// ---- K3: exclusive scan of deg -> rowptr (single block) ----
#define SCAN_T 1024
#define SCAN_V 8
__global__ void k_scan(const int* __restrict__ deg, int* __restrict__ rowptr, int n) {
    __shared__ int sh[SCAN_T];
    __shared__ int s_carry;
    int tid = threadIdx.x;
    if (tid == 0) s_carry = 0;
    __syncthreads();
    for (int base = 0; base < n; base += SCAN_T * SCAN_V) {
        int vals[SCAN_V];
        int idx0 = base + tid * SCAN_V;
        int local = 0;
        #pragma unroll
        for (int i = 0; i < SCAN_V; ++i) {
            int ix = idx0 + i;
            int v = (ix < n) ? deg[ix] : 0;
            vals[i] = local;
            local += v;
        }
        sh[tid] = local;
        __syncthreads();
        for (int off = 1; off < SCAN_T; off <<= 1) {
            int t = (tid >= off) ? sh[tid - off] : 0;
            __syncthreads();
            sh[tid] += t;
            __syncthreads();
        }
        int texc = ((tid > 0) ? sh[tid - 1] : 0) + s_carry;
        #pragma unroll
        for (int i = 0; i < SCAN_V; ++i) {
            int ix = idx0 + i;
            if (ix < n) rowptr[ix] = texc + vals[i];
        }
        __syncthreads();
        if (tid == 0) s_carry += sh[SCAN_T - 1];
        __syncthreads();
    }
    if (tid == 0) rowptr[n] = s_carry;
}

// ---- K4: partial counts -> absolute offsets (in-place scan over chunk axis) ----
__global__ void k_offs(int* __restrict__ partial, const int* __restrict__ rowptr, int N) {
    int n = blockIdx.x * 256 + threadIdx.x;
    if (n >= N) return;
    int run = rowptr[n];
    #pragma unroll
    for (int c = 0; c < NCHUNK; ++c) {
        size_t ix = (size_t)c * N + n;
        int t = partial[ix];
        partial[ix] = run;
        run += t;
    }
}

// ---- K5: place edges into col via LDS cursors; rsum partials into offs (dead) ----
__launch_bounds__(256)
__global__ void k_place(const int* __restrict__ src, const int* __restrict__ dst,
                        const float* __restrict__ dinv, int* __restrict__ offs,
                        int* __restrict__ col, int N, int E, int chunkE, int sliceN) {
    int c = blockIdx.x >> 3, s = blockIdx.x & (NSLICE - 1);
    int nbase = s * sliceN;
    __shared__ int cur[SLICE_MAX];
    __shared__ float rs[SLICE_MAX];
    for (int j = threadIdx.x; j < sliceN; j += 256) {
        int n = nbase + j;
        cur[j] = (n < N) ? offs[(size_t)c * N + n] : 0;
        rs[j] = 0.f;
    }
    __syncthreads();
    int e0 = c * chunkE, e1 = min(e0 + chunkE, E);
    int ne = e1 - e0;
    const int4* s4 = (const int4*)(src + e0);
    const int4* d4 = (const int4*)(dst + e0);
    int n4 = ne >> 2;
    for (int i = threadIdx.x; i < n4; i += 256) {
        int4 sv = s4[i];
        int4 dv = d4[i];
        unsigned qd, qs;
        qd = (unsigned)(dv.x - nbase);
        if (qd < (unsigned)sliceN) { int p = atomicAdd(&cur[qd], 1); col[p] = sv.x; }
        qs = (unsigned)(sv.x - nbase);
        if (qs < (unsigned)sliceN) atomicAdd(&rs[qs], dinv[dv.x]);
        qd = (unsigned)(dv.y - nbase);
        if (qd < (unsigned)sliceN) { int p = atomicAdd(&cur[qd], 1); col[p] = sv.y; }
        qs = (unsigned)(sv.y - nbase);
        if (qs < (unsigned)sliceN) atomicAdd(&rs[qs], dinv[dv.y]);
        qd = (unsigned)(dv.z - nbase);
        if (qd < (unsigned)sliceN) { int p = atomicAdd(&cur[qd], 1); col[p] = sv.z; }
        qs = (unsigned)(sv.z - nbase);
        if (qs < (unsigned)sliceN) atomicAdd(&rs[qs], dinv[dv.z]);
        qd = (unsigned)(dv.w - nbase);
        if (qd < (unsigned)sliceN) { int p = atomicAdd(&cur[qd], 1); col[p] = sv.w; }
        qs = (unsigned)(sv.w - nbase);
        if (qs < (unsigned)sliceN) atomicAdd(&rs[qs], dinv[dv.w]);
    }
    if (threadIdx.x < (ne & 3)) {
        int e = e0 + (n4 << 2) + threadIdx.x;
        int sv = src[e], dv = dst[e];
        unsigned qd = (unsigned)(dv - nbase);
        if (qd < (unsigned)sliceN) { int p = atomicAdd(&cur[qd], 1); col[p] = sv; }
        unsigned qs = (unsigned)(sv - nbase);
        if (qs < (unsigned)sliceN) atomicAdd(&rs[qs], dinv[dv]);
    }
    __syncthreads();
    float* prs = (float*)offs;   // offs[c][this slice] is dead after load -> reuse
    for (int j = threadIdx.x; j < sliceN; j += 256) {
        int n = nbase + j;
        if (n < N) prs[(size_t)c * N + n] = rs[j];
    }
}

// ---- K6: rsum = sum over chunk partials ----
__global__ void k_rsum(const float* __restrict__ prs, float* __restrict__ rsum, int N) {
    int n = blockIdx.x * 256 + threadIdx.x;
    if (n >= N) return;
    float s = 0.f;
    #pragma unroll
    for (int c = 0; c < NCHUNK; ++c) s += prs[(size_t)c * N + n];
    rsum[n] = s;
}

// ---- g = (x @ W1) * dinv[row]   (M=50000, K=128, Ncols=96) ----
__launch_bounds__(256)
__global__ void k_gemm(const float* __restrict__ x, const float* __restrict__ W1,
                       const float* __restrict__ dinv, float* __restrict__ g, int n) {
    __shared__ float Ws[128 * 96];
    int tid = threadIdx.x;
    {
        const float4* wsrc = (const float4*)W1;
        float4* wdst = (float4*)Ws;
        #pragma unroll
        for (int i = 0; i < 12; ++i) wdst[tid + 256 * i] = wsrc[tid + 256 * i];
    }
    __syncthreads();

    int tx = tid & 7;
    int ty = tid >> 3;
    int r0 = blockIdx.x * 64 + ty * 2;
    int r1 = r0 + 1;
    bool v0 = r0 < n, v1 = r1 < n;
    const float4* x0 = (const float4*)(x + (size_t)(v0 ? r0 : 0) * 128);
    const float4* x1 = (const float4*)(x + (size_t)(v1 ? r1 : 0) * 128);

    float4 acc[2][3];
    #pragma unroll
    for (int i = 0; i < 2; ++i)
        #pragma unroll
        for (int j = 0; j < 3; ++j) acc[i][j] = make_float4(0.f, 0.f, 0.f, 0.f);

    #pragma unroll 4
    for (int k4 = 0; k4 < 32; ++k4) {
        float4 a0 = x0[k4];
        float4 a1 = x1[k4];
        #pragma unroll
        for (int kk = 0; kk < 4; ++kk) {
            const float* wrow = &Ws[(k4 * 4 + kk) * 96 + tx * 12];
            float4 b0 = *(const float4*)(wrow);
            float4 b1 = *(const float4*)(wrow + 4);
            float4 b2 = *(const float4*)(wrow + 8);
            float av0 = (kk == 0) ? a0.x : (kk == 1) ? a0.y : (kk == 2) ? a0.z : a0.w;
            float av1 = (kk == 0) ? a1.x : (kk == 1) ? a1.y : (kk == 2) ? a1.z : a1.w;
            fma4(acc[0][0], av0, b0); fma4(acc[0][1], av0, b1); fma4(acc[0][2], av0, b2);
            fma4(acc[1][0], av1, b0); fma4(acc[1][1], av1, b1); fma4(acc[1][2], av1, b2);
        }
    }

    if (v0) {
        float dv = dinv[r0];
        float4* o = (float4*)(g + (size_t)r0 * 96 + tx * 12);
        float4 t;
        t = acc[0][0]; t.x *= dv; t.y *= dv; t.z *= dv; t.w *= dv; o[0] = t;
        t = acc[0][1]; t.x *= dv; t.y *= dv; t.z *= dv; t.w *= dv; o[1] = t;
        t = acc[0][2]; t.x *= dv; t.y *= dv; t.z *= dv; t.w *= dv; o[2] = t;
    }
    if (v1) {
        float dv = dinv[r1];
        float4* o = (float4*)(g + (size_t)r1 * 96 + tx * 12);
        float4 t;
        t = acc[1][0]; t.x *= dv; t.y *= dv; t.z *= dv; t.w *= dv; o[0] = t;
        t = acc[1][1]; t.x *= dv; t.y *= dv; t.z *= dv; t.w *= dv; o[1] = t;
        t = acc[1][2]; t.x *= dv; t.y *= dv; t.z *= dv; t.w *= dv; o[2] = t;
    }
}

// ---- per-node gather + fused bias/relu/c[d] weight + block partial of v ----
#define AGG_NODES 16
#define AGG_T (AGG_NODES * 24)
__launch_bounds__(AGG_T)
__global__ void k_agg(const float4* __restrict__ g4, const int* __restrict__ col,
                      const int* __restrict__ rowptr, const float* __restrict__ dinv,
                      const float* __restrict__ rsum, const float* __restrict__ b1,
                      float* __restrict__ v_part, int n) {
    int tid = threadIdx.x;
    int nl = tid / 24;
    int ch = tid % 24;
    int d = blockIdx.x * AGG_NODES + nl;

    __shared__ float4 sh[AGG_NODES][24];

    float4 contrib = make_float4(0.f, 0.f, 0.f, 0.f);
    if (d < n) {
        float dd = dinv[d];
        int e0 = rowptr[d], e1 = rowptr[d + 1];
        float4 a0 = make_float4(0.f, 0.f, 0.f, 0.f);
        float4 a1 = make_float4(0.f, 0.f, 0.f, 0.f);
        int e = e0;
        for (; e + 2 <= e1; e += 2) {
            int s0 = col[e], s1 = col[e + 1];
            float4 gv0 = g4[(size_t)s0 * 24 + ch];
            float4 gv1 = g4[(size_t)s1 * 24 + ch];
            a0.x += gv0.x; a0.y += gv0.y; a0.z += gv0.z; a0.w += gv0.w;
            a1.x += gv1.x; a1.y += gv1.y; a1.z += gv1.z; a1.w += gv1.w;
        }
        if (e < e1) {
            float4 gv = g4[(size_t)col[e] * 24 + ch];
            a0.x += gv.x; a0.y += gv.y; a0.z += gv.z; a0.w += gv.w;
        }
        float4 gd = g4[(size_t)d * 24 + ch];   // analytic self-loop: g[d]*dinv[d]
        float4 b1c = ((const float4*)b1)[ch];
        float cd = dd * (dd + rsum[d]);
        float hx = fmaxf(fmaf(dd, a0.x + a1.x + gd.x, b1c.x), 0.f);
        float hy = fmaxf(fmaf(dd, a0.y + a1.y + gd.y, b1c.y), 0.f);
        float hz = fmaxf(fmaf(dd, a0.z + a1.z + gd.z, b1c.z), 0.f);
        float hw = fmaxf(fmaf(dd, a0.w + a1.w + gd.w, b1c.w), 0.f);
        contrib = make_float4(cd * hx, cd * hy, cd * hz, cd * hw);
    }
    sh[nl][ch] = contrib;
    __syncthreads();
    #pragma unroll
    for (int off = 8; off >= 1; off >>= 1) {
        if (nl < off) {
            float4 a = sh[nl][ch];
            float4 b = sh[nl + off][ch];
            a.x += b.x; a.y += b.y; a.z += b.z; a.w += b.w;
            sh[nl][ch] = a;
        }
        __syncthreads();
    }
    if (tid < 24) {
        ((float4*)(v_part + (size_t)blockIdx.x * 96))[tid] = sh[0][tid];
    }
}

// ---- reduce v_part -> v[96] ----
__global__ void k_vred(const float* __restrict__ vp, float* __restrict__ v, int nb) {
    int j = blockIdx.x;
    float s = 0.f;
    for (int i = threadIdx.x; i < nb; i += 256) s += vp[(size_t)i * 96 + j];
    __shared__ float sh[256];
    sh[threadIdx.x] = s;
    __syncthreads();
    for (int off = 128; off; off >>= 1) {
        if (threadIdx.x < off) sh[threadIdx.x] += sh[threadIdx.x + off];
        __syncthreads();
    }
    if (threadIdx.x == 0) v[j] = sh[0];
}

// ---- mu = v@W_mu + N*b_mu ; logvar = v@W_lv + N*b_lv ----
__global__ void k_out(const float* __restrict__ v,
                      const float* __restrict__ Wmu, const float* __restrict__ bmu,
                      const float* __restrict__ Wlv, const float* __restrict__ blv,
                      float* __restrict__ out, float nN) {
    int tid = threadIdx.x;
    const float* W = (tid < 64) ? Wmu : Wlv;
    const float* b = (tid < 64) ? bmu : blv;
    int j = tid & 63;
    float s = 0.f;
    #pragma unroll
    for (int k = 0; k < 96; ++k) s = fmaf(v[k], W[k * 64 + j], s);
    out[tid] = s + nN * b[j];
}

extern "C" void kernel_launch(void* const* d_in, const int* in_sizes, int n_in,
                              void* d_out, int out_size, void* d_ws, size_t ws_size,
                              hipStream_t stream) {
    const float* x   = (const float*)d_in[0];
    const int*   ei  = (const int*)d_in[1];
    const float* W1  = (const float*)d_in[2];
    const float* b1  = (const float*)d_in[3];
    const float* Wmu = (const float*)d_in[4];
    const float* bmu = (const float*)d_in[5];
    const float* Wlv = (const float*)d_in[6];
    const float* blv = (const float*)d_in[7];
    float* out = (float*)d_out;

    const int N = in_sizes[0] / 128;   // 50000
    const int E = in_sizes[1] / 2;     // 800000
    const int* src = ei;
    const int* dst = ei + E;

    // chunkE: multiple of 4 for int4 loads; sliceN <= SLICE_MAX
    const int chunkE = (((E + NCHUNK - 1) / NCHUNK) + 3) & ~3;   // 12500
    const int sliceN = (N + NSLICE - 1) / NSLICE;                // 6250

    size_t off = 0;
    auto alloc = [&](size_t bytes) -> char* {
        off = (off + 255) & ~(size_t)255;
        char* p = (char*)d_ws + off;
        off += bytes;
        return p;
    };
    int*   partial = (int*)alloc((size_t)NCHUNK * N * 4);   // 12.8 MB (counts->offs->rsum partials)
    int*   rowptr  = (int*)alloc((size_t)(N + 1) * 4);
    int*   col     = (int*)alloc((size_t)E * 4);
    int*   deg     = (int*)alloc((size_t)N * 4);
    float* dinv    = (float*)alloc((size_t)N * 4);
    float* rsum    = (float*)alloc((size_t)N * 4);
    float* g       = (float*)alloc((size_t)N * 96 * 4);
    const int nAggBlocks = (N + AGG_NODES - 1) / AGG_NODES;
    float* v_part  = (float*)alloc((size_t)nAggBlocks * 96 * 4);
    float* v       = (float*)alloc(96 * 4);

    const int gN = (N + 255) / 256;

    k_count<<<NCHUNK * NSLICE, 256, 0, stream>>>(dst, partial, N, E, chunkE, sliceN);
    k_degdinv<<<gN, 256, 0, stream>>>(partial, deg, dinv, N);
    k_scan<<<1, SCAN_T, 0, stream>>>(deg, rowptr, N);
    k_offs<<<gN, 256, 0, stream>>>(partial, rowptr, N);
    k_place<<<NCHUNK * NSLICE, 256, 0, stream>>>(src, dst, dinv, partial, col, N, E, chunkE, sliceN);
    k_rsum<<<gN, 256, 0, stream>>>((const float*)partial, rsum, N);
    k_gemm<<<(N + 63) / 64, 256, 0, stream>>>(x, W1, dinv, g, N);
    k_agg<<<nAggBlocks, AGG_T, 0, stream>>>((const float4*)g, col, rowptr, dinv,
                                            rsum, b1, v_part, N);
    k_vred<<<96, 256, 0, stream>>>(v_part, v, nAggBlocks);
    k_out<<<1, 128, 0, stream>>>(v, Wmu, bmu, Wlv, blv, out, (float)N);
}

// Round 4
// 160.170 us; speedup vs baseline: 1.6974x; 1.3196x over previous
//
#include <hip/hip_runtime.h>
#include <hip/hip_bf16.h>

// GCN encoder, N=50000, E=800000, 128 -> 96 (relu) -> sum-pooled 64+64.
// Sum-pooled layer 2: out = (sum_u c[u]*h[u]) @ W + N*b,
//   c[u] = dinv[u]*(dinv[u] + rsum[u]),  rsum[u] = sum_{e: src=u} dinv[dst_e].
// Layer 1 with g[u] = (xW1)[u]*dinv[u]:
//   h[d] = relu( dinv[d]*(sum_{e->d} g[src] + g[d]) + b1 )
// CSR build = 2-level counting sort (64 edge-chunks x 8 node-slices), zero
// device atomics. rowptr scan is hierarchical (blocksum -> 1-block scan ->
// per-block LDS scan fused into k_offs); the old single-block k_scan was
// 55us at 0.16% occupancy.

#define NTHREADS 256
#define NCHUNK 64
#define NSLICE 8
#define SLICE_MAX 6272   // LDS hist capacity; N <= 8*6272

__device__ inline void fma4(float4& c, float a, const float4& b) {
    c.x = fmaf(a, b.x, c.x); c.y = fmaf(a, b.y, c.y);
    c.z = fmaf(a, b.z, c.z); c.w = fmaf(a, b.w, c.w);
}

// ---- K1: per-(chunk,slice) dst histogram via LDS ----
__launch_bounds__(256)
__global__ void k_count(const int* __restrict__ dst, int* __restrict__ partial,
                        int N, int E, int chunkE, int sliceN) {
    int c = blockIdx.x >> 3, s = blockIdx.x & (NSLICE - 1);
    int nbase = s * sliceN;
    __shared__ int hist[SLICE_MAX];
    for (int j = threadIdx.x; j < sliceN; j += 256) hist[j] = 0;
    __syncthreads();
    int e0 = c * chunkE, e1 = min(e0 + chunkE, E);
    int ne = e1 - e0;
    const int4* d4 = (const int4*)(dst + e0);
    int n4 = ne >> 2;
    for (int i = threadIdx.x; i < n4; i += 256) {
        int4 d = d4[i];
        unsigned q;
        q = (unsigned)(d.x - nbase); if (q < (unsigned)sliceN) atomicAdd(&hist[q], 1);
        q = (unsigned)(d.y - nbase); if (q < (unsigned)sliceN) atomicAdd(&hist[q], 1);
        q = (unsigned)(d.z - nbase); if (q < (unsigned)sliceN) atomicAdd(&hist[q], 1);
        q = (unsigned)(d.w - nbase); if (q < (unsigned)sliceN) atomicAdd(&hist[q], 1);
    }
    if (threadIdx.x < (ne & 3)) {
        int d = dst[e0 + (n4 << 2) + threadIdx.x];
        unsigned q = (unsigned)(d - nbase);
        if (q < (unsigned)sliceN) atomicAdd(&hist[q], 1);
    }
    __syncthreads();
    for (int j = threadIdx.x; j < sliceN; j += 256) {
        int n = nbase + j;
        if (n < N) partial[(size_t)c * N + n] = hist[j];
    }
}

// ---- K2: deg = sum over chunks; dinv; per-block sum of deg ----
__launch_bounds__(256)
__global__ void k_degdinv(const int* __restrict__ partial, int* __restrict__ deg,
                          float* __restrict__ dinv, int* __restrict__ blocksum, int N) {
    int tid = threadIdx.x;
    int n = blockIdx.x * 256 + tid;
    int s = 0;
    if (n < N) {
        #pragma unroll
        for (int c = 0; c < NCHUNK; ++c) s += partial[(size_t)c * N + n];
        deg[n] = s;
        dinv[n] = rsqrtf((float)(s + 1));
    }
    __shared__ int sh[256];
    sh[tid] = s;
    __syncthreads();
    #pragma unroll
    for (int off = 128; off; off >>= 1) {
        if (tid < off) sh[tid] += sh[tid + off];
        __syncthreads();
    }
    if (tid == 0) blocksum[blockIdx.x] = sh[0];
}

// ---- K3: exclusive scan of block sums (nb <= 256), one block ----
__global__ void k_bscan(const int* __restrict__ blocksum, int* __restrict__ blockoff,
                        int* __restrict__ rowptrN, int nb) {
    __shared__ int sh[256];
    int tid = threadIdx.x;
    int v = (tid < nb) ? blocksum[tid] : 0;
    sh[tid] = v;
    __syncthreads();
    for (int off = 1; off < 256; off <<= 1) {
        int t = (tid >= off) ? sh[tid - off] : 0;
        __syncthreads();
        sh[tid] += t;
        __syncthreads();
    }
    if (tid < nb) blockoff[tid] = sh[tid] - v;   // exclusive
    if (tid == nb - 1) *rowptrN = sh[tid];       // total = E
}

// ---- K4: per-block LDS scan of deg -> rowptr; partial counts -> abs offsets ----
__launch_bounds__(256)
__global__ void k_offs(int* __restrict__ partial, const int* __restrict__ deg,
                       const int* __restrict__ blockoff, int* __restrict__ rowptr, int N) {
    int tid = threadIdx.x;
    int n = blockIdx.x * 256 + tid;
    int v = (n < N) ? deg[n] : 0;
    __shared__ int sh[256];
    sh[tid] = v;
    __syncthreads();
    for (int off = 1; off < 256; off <<= 1) {
        int t = (tid >= off) ? sh[tid - off] : 0;
        __syncthreads();
        sh[tid] += t;
        __syncthreads();
    }
    int run = blockoff[blockIdx.x] + sh[tid] - v;   // exclusive prefix
    if (n < N) {
        rowptr[n] = run;
        #pragma unroll
        for (int c = 0; c < NCHUNK; ++c) {
            size_t ix = (size_t)c * N + n;
            int t = partial[ix];
            partial[ix] = run;
            run += t;
        }
    }
}

// ---- K5: place edges into col via LDS cursors; rsum partials into offs (dead) ----
__launch_bounds__(256)
__global__ void k_place(const int* __restrict__ src, const int* __restrict__ dst,
                        const float* __restrict__ dinv, int* __restrict__ offs,
                        int* __restrict__ col, int N, int E, int chunkE, int sliceN) {
    int c = blockIdx.x >> 3, s = blockIdx.x & (NSLICE - 1);
    int nbase = s * sliceN;
    __shared__ int cur[SLICE_MAX];
    __shared__ float rs[SLICE_MAX];
    for (int j = threadIdx.x; j < sliceN; j += 256) {
        int n = nbase + j;
        cur[j] = (n < N) ? offs[(size_t)c * N + n] : 0;
        rs[j] = 0.f;
    }
    __syncthreads();
    int e0 = c * chunkE, e1 = min(e0 + chunkE, E);
    int ne = e1 - e0;
    const int4* s4 = (const int4*)(src + e0);
    const int4* d4 = (const int4*)(dst + e0);
    int n4 = ne >> 2;
    for (int i = threadIdx.x; i < n4; i += 256) {
        int4 sv = s4[i];
        int4 dv = d4[i];
        unsigned qd, qs;
        qd = (unsigned)(dv.x - nbase);
        if (qd < (unsigned)sliceN) { int p = atomicAdd(&cur[qd], 1); col[p] = sv.x; }
        qs = (unsigned)(sv.x - nbase);
        if (qs < (unsigned)sliceN) atomicAdd(&rs[qs], dinv[dv.x]);
        qd = (unsigned)(dv.y - nbase);
        if (qd < (unsigned)sliceN) { int p = atomicAdd(&cur[qd], 1); col[p] = sv.y; }
        qs = (unsigned)(sv.y - nbase);
        if (qs < (unsigned)sliceN) atomicAdd(&rs[qs], dinv[dv.y]);
        qd = (unsigned)(dv.z - nbase);
        if (qd < (unsigned)sliceN) { int p = atomicAdd(&cur[qd], 1); col[p] = sv.z; }
        qs = (unsigned)(sv.z - nbase);
        if (qs < (unsigned)sliceN) atomicAdd(&rs[qs], dinv[dv.z]);
        qd = (unsigned)(dv.w - nbase);
        if (qd < (unsigned)sliceN) { int p = atomicAdd(&cur[qd], 1); col[p] = sv.w; }
        qs = (unsigned)(sv.w - nbase);
        if (qs < (unsigned)sliceN) atomicAdd(&rs[qs], dinv[dv.w]);
    }
    if (threadIdx.x < (ne & 3)) {
        int e = e0 + (n4 << 2) + threadIdx.x;
        int sv = src[e], dv = dst[e];
        unsigned qd = (unsigned)(dv - nbase);
        if (qd < (unsigned)sliceN) { int p = atomicAdd(&cur[qd], 1); col[p] = sv; }
        unsigned qs = (unsigned)(sv - nbase);
        if (qs < (unsigned)sliceN) atomicAdd(&rs[qs], dinv[dv]);
    }
    __syncthreads();
    float* prs = (float*)offs;   // offs[c][this slice] dead after load -> reuse
    for (int j = threadIdx.x; j < sliceN; j += 256) {
        int n = nbase + j;
        if (n < N) prs[(size_t)c * N + n] = rs[j];
    }
}

// ---- K6: rsum = sum over chunk partials ----
__global__ void k_rsum(const float* __restrict__ prs, float* __restrict__ rsum, int N) {
    int n = blockIdx.x * 256 + threadIdx.x;
    if (n >= N) return;
    float s = 0.f;
    #pragma unroll
    for (int c = 0; c < NCHUNK; ++c) s += prs[(size_t)c * N + n];
    rsum[n] = s;
}

// ---- g = (x @ W1) * dinv[row]   (M=50000, K=128, Ncols=96) ----
__launch_bounds__(256)
__global__ void k_gemm(const float* __restrict__ x, const float* __restrict__ W1,
                       const float* __restrict__ dinv, float* __restrict__ g, int n) {
    __shared__ float Ws[128 * 96];
    int tid = threadIdx.x;
    {
        const float4* wsrc = (const float4*)W1;
        float4* wdst = (float4*)Ws;
        #pragma unroll
        for (int i = 0; i < 12; ++i) wdst[tid + 256 * i] = wsrc[tid + 256 * i];
    }
    __syncthreads();

    int tx = tid & 7;
    int ty = tid >> 3;
    int r0 = blockIdx.x * 64 + ty * 2;
    int r1 = r0 + 1;
    bool v0 = r0 < n, v1 = r1 < n;
    const float4* x0 = (const float4*)(x + (size_t)(v0 ? r0 : 0) * 128);
    const float4* x1 = (const float4*)(x + (size_t)(v1 ? r1 : 0) * 128);

    float4 acc[2][3];
    #pragma unroll
    for (int i = 0; i < 2; ++i)
        #pragma unroll
        for (int j = 0; j < 3; ++j) acc[i][j] = make_float4(0.f, 0.f, 0.f, 0.f);

    #pragma unroll 4
    for (int k4 = 0; k4 < 32; ++k4) {
        float4 a0 = x0[k4];
        float4 a1 = x1[k4];
        #pragma unroll
        for (int kk = 0; kk < 4; ++kk) {
            const float* wrow = &Ws[(k4 * 4 + kk) * 96 + tx * 12];
            float4 b0 = *(const float4*)(wrow);
            float4 b1 = *(const float4*)(wrow + 4);
            float4 b2 = *(const float4*)(wrow + 8);
            float av0 = (kk == 0) ? a0.x : (kk == 1) ? a0.y : (kk == 2) ? a0.z : a0.w;
            float av1 = (kk == 0) ? a1.x : (kk == 1) ? a1.y : (kk == 2) ? a1.z : a1.w;
            fma4(acc[0][0], av0, b0); fma4(acc[0][1], av0, b1); fma4(acc[0][2], av0, b2);
            fma4(acc[1][0], av1, b0); fma4(acc[1][1], av1, b1); fma4(acc[1][2], av1, b2);
        }
    }

    if (v0) {
        float dv = dinv[r0];
        float4* o = (float4*)(g + (size_t)r0 * 96 + tx * 12);
        float4 t;
        t = acc[0][0]; t.x *= dv; t.y *= dv; t.z *= dv; t.w *= dv; o[0] = t;
        t = acc[0][1]; t.x *= dv; t.y *= dv; t.z *= dv; t.w *= dv; o[1] = t;
        t = acc[0][2]; t.x *= dv; t.y *= dv; t.z *= dv; t.w *= dv; o[2] = t;
    }
    if (v1) {
        float dv = dinv[r1];
        float4* o = (float4*)(g + (size_t)r1 * 96 + tx * 12);
        float4 t;
        t = acc[1][0]; t.x *= dv; t.y *= dv; t.z *= dv; t.w *= dv; o[0] = t;
        t = acc[1][1]; t.x *= dv; t.y *= dv; t.z *= dv; t.w *= dv; o[1] = t;
        t = acc[1][2]; t.x *= dv; t.y *= dv; t.z *= dv; t.w *= dv; o[2] = t;
    }
}

// ---- per-node gather + fused bias/relu/c[d] weight + block partial of v ----
#define AGG_NODES 16
#define AGG_T (AGG_NODES * 24)
__launch_bounds__(AGG_T)
__global__ void k_agg(const float4* __restrict__ g4, const int* __restrict__ col,
                      const int* __restrict__ rowptr, const float* __restrict__ dinv,
                      const float* __restrict__ rsum, const float* __restrict__ b1,
                      float* __restrict__ v_part, int n) {
    int tid = threadIdx.x;
    int nl = tid / 24;
    int ch = tid % 24;
    int d = blockIdx.x * AGG_NODES + nl;

    __shared__ float4 sh[AGG_NODES][24];

    float4 contrib = make_float4(0.f, 0.f, 0.f, 0.f);
    if (d < n) {
        float dd = dinv[d];
        int e0 = rowptr[d], e1 = rowptr[d + 1];
        float4 a0 = make_float4(0.f, 0.f, 0.f, 0.f);
        float4 a1 = make_float4(0.f, 0.f, 0.f, 0.f);
        int e = e0;
        for (; e + 2 <= e1; e += 2) {
            int s0 = col[e], s1 = col[e + 1];
            float4 gv0 = g4[(size_t)s0 * 24 + ch];
            float4 gv1 = g4[(size_t)s1 * 24 + ch];
            a0.x += gv0.x; a0.y += gv0.y; a0.z += gv0.z; a0.w += gv0.w;
            a1.x += gv1.x; a1.y += gv1.y; a1.z += gv1.z; a1.w += gv1.w;
        }
        if (e < e1) {
            float4 gv = g4[(size_t)col[e] * 24 + ch];
            a0.x += gv.x; a0.y += gv.y; a0.z += gv.z; a0.w += gv.w;
        }
        float4 gd = g4[(size_t)d * 24 + ch];   // analytic self-loop: g[d]*dinv[d]
        float4 b1c = ((const float4*)b1)[ch];
        float cd = dd * (dd + rsum[d]);
        float hx = fmaxf(fmaf(dd, a0.x + a1.x + gd.x, b1c.x), 0.f);
        float hy = fmaxf(fmaf(dd, a0.y + a1.y + gd.y, b1c.y), 0.f);
        float hz = fmaxf(fmaf(dd, a0.z + a1.z + gd.z, b1c.z), 0.f);
        float hw = fmaxf(fmaf(dd, a0.w + a1.w + gd.w, b1c.w), 0.f);
        contrib = make_float4(cd * hx, cd * hy, cd * hz, cd * hw);
    }
    sh[nl][ch] = contrib;
    __syncthreads();
    #pragma unroll
    for (int off = 8; off >= 1; off >>= 1) {
        if (nl < off) {
            float4 a = sh[nl][ch];
            float4 b = sh[nl + off][ch];
            a.x += b.x; a.y += b.y; a.z += b.z; a.w += b.w;
            sh[nl][ch] = a;
        }
        __syncthreads();
    }
    if (tid < 24) {
        ((float4*)(v_part + (size_t)blockIdx.x * 96))[tid] = sh[0][tid];
    }
}

// ---- reduce v_part -> v[96] ----
__global__ void k_vred(const float* __restrict__ vp, float* __restrict__ v, int nb) {
    int j = blockIdx.x;
    float s = 0.f;
    for (int i = threadIdx.x; i < nb; i += 256) s += vp[(size_t)i * 96 + j];
    __shared__ float sh[256];
    sh[threadIdx.x] = s;
    __syncthreads();
    for (int off = 128; off; off >>= 1) {
        if (threadIdx.x < off) sh[threadIdx.x] += sh[threadIdx.x + off];
        __syncthreads();
    }
    if (threadIdx.x == 0) v[j] = sh[0];
}

// ---- mu = v@W_mu + N*b_mu ; logvar = v@W_lv + N*b_lv ----
__global__ void k_out(const float* __restrict__ v,
                      const float* __restrict__ Wmu, const float* __restrict__ bmu,
                      const float* __restrict__ Wlv, const float* __restrict__ blv,
                      float* __restrict__ out, float nN) {
    int tid = threadIdx.x;
    const float* W = (tid < 64) ? Wmu : Wlv;
    const float* b = (tid < 64) ? bmu : blv;
    int j = tid & 63;
    float s = 0.f;
    #pragma unroll
    for (int k = 0; k < 96; ++k) s = fmaf(v[k], W[k * 64 + j], s);
    out[tid] = s + nN * b[j];
}

extern "C" void kernel_launch(void* const* d_in, const int* in_sizes, int n_in,
                              void* d_out, int out_size, void* d_ws, size_t ws_size,
                              hipStream_t stream) {
    const float* x   = (const float*)d_in[0];
    const int*   ei  = (const int*)d_in[1];
    const float* W1  = (const float*)d_in[2];
    const float* b1  = (const float*)d_in[3];
    const float* Wmu = (const float*)d_in[4];
    const float* bmu = (const float*)d_in[5];
    const float* Wlv = (const float*)d_in[6];
    const float* blv = (const float*)d_in[7];
    float* out = (float*)d_out;

    const int N = in_sizes[0] / 128;   // 50000
    const int E = in_sizes[1] / 2;     // 800000
    const int* src = ei;
    const int* dst = ei + E;

    const int chunkE = (((E + NCHUNK - 1) / NCHUNK) + 3) & ~3;   // 12500
    const int sliceN = (N + NSLICE - 1) / NSLICE;                // 6250
    const int gN = (N + 255) / 256;                              // 196

    size_t off = 0;
    auto alloc = [&](size_t bytes) -> char* {
        off = (off + 255) & ~(size_t)255;
        char* p = (char*)d_ws + off;
        off += bytes;
        return p;
    };
    int*   partial  = (int*)alloc((size_t)NCHUNK * N * 4);   // counts->offs->rsum partials
    int*   rowptr   = (int*)alloc((size_t)(N + 1) * 4);
    int*   col      = (int*)alloc((size_t)E * 4);
    int*   deg      = (int*)alloc((size_t)N * 4);
    float* dinv     = (float*)alloc((size_t)N * 4);
    float* rsum     = (float*)alloc((size_t)N * 4);
    int*   blocksum = (int*)alloc((size_t)gN * 4);
    int*   blockoff = (int*)alloc((size_t)gN * 4);
    float* g        = (float*)alloc((size_t)N * 96 * 4);
    const int nAggBlocks = (N + AGG_NODES - 1) / AGG_NODES;
    float* v_part   = (float*)alloc((size_t)nAggBlocks * 96 * 4);
    float* v        = (float*)alloc(96 * 4);

    k_count<<<NCHUNK * NSLICE, 256, 0, stream>>>(dst, partial, N, E, chunkE, sliceN);
    k_degdinv<<<gN, 256, 0, stream>>>(partial, deg, dinv, blocksum, N);
    k_bscan<<<1, 256, 0, stream>>>(blocksum, blockoff, rowptr + N, gN);
    k_offs<<<gN, 256, 0, stream>>>(partial, deg, blockoff, rowptr, N);
    k_place<<<NCHUNK * NSLICE, 256, 0, stream>>>(src, dst, dinv, partial, col, N, E, chunkE, sliceN);
    k_rsum<<<gN, 256, 0, stream>>>((const float*)partial, rsum, N);
    k_gemm<<<(N + 63) / 64, 256, 0, stream>>>(x, W1, dinv, g, N);
    k_agg<<<nAggBlocks, AGG_T, 0, stream>>>((const float4*)g, col, rowptr, dinv,
                                            rsum, b1, v_part, N);
    k_vred<<<96, 256, 0, stream>>>(v_part, v, nAggBlocks);
    k_out<<<1, 128, 0, stream>>>(v, Wmu, bmu, Wlv, blv, out, (float)N);
}

// Round 5
// 143.756 us; speedup vs baseline: 1.8912x; 1.1142x over previous
//
#include <hip/hip_runtime.h>
#include <hip/hip_fp16.h>

// GCN encoder, N=50000, E=800000, 128 -> 96 (relu) -> sum-pooled 64+64.
// Sum-pooled layer 2: out = (sum_u c[u]*h[u]) @ W + N*b,
//   c[u] = dinv[u]*(dinv[u] + rsum[u]),  rsum[u] = sum_{e: src=u} dinv[dst_e].
// Layer 1 with g[u] = (xW1)[u]*dinv[u]:
//   h[d] = relu( dinv[d]*(sum_{e->d} g[src] + g[d]) + b1 )
// g stored in FP16: gather volume 307->154 MB logical; g fits 2x better in L2.
// CSR build = 2-level counting sort, zero device atomics; hierarchical scan.

#define NTHREADS 256
#define NCHUNK 64
#define NSLICE 8
#define SLICE_MAX 6272   // LDS hist capacity; N <= 8*6272

__device__ inline void fma4(float4& c, float a, const float4& b) {
    c.x = fmaf(a, b.x, c.x); c.y = fmaf(a, b.y, c.y);
    c.z = fmaf(a, b.z, c.z); c.w = fmaf(a, b.w, c.w);
}

__device__ inline unsigned f2h(float a, float b) {
    __half2 h = __floats2half2_rn(a, b);
    return *reinterpret_cast<unsigned*>(&h);
}
__device__ inline float2 h2f(unsigned u) {
    __half2 h = *reinterpret_cast<__half2*>(&u);
    return __half22float2(h);
}

// ---- K1: per-(chunk,slice) dst histogram via LDS ----
__launch_bounds__(256)
__global__ void k_count(const int* __restrict__ dst, int* __restrict__ partial,
                        int N, int E, int chunkE, int sliceN) {
    int c = blockIdx.x >> 3, s = blockIdx.x & (NSLICE - 1);
    int nbase = s * sliceN;
    __shared__ int hist[SLICE_MAX];
    for (int j = threadIdx.x; j < sliceN; j += 256) hist[j] = 0;
    __syncthreads();
    int e0 = c * chunkE, e1 = min(e0 + chunkE, E);
    int ne = e1 - e0;
    const int4* d4 = (const int4*)(dst + e0);
    int n4 = ne >> 2;
    for (int i = threadIdx.x; i < n4; i += 256) {
        int4 d = d4[i];
        unsigned q;
        q = (unsigned)(d.x - nbase); if (q < (unsigned)sliceN) atomicAdd(&hist[q], 1);
        q = (unsigned)(d.y - nbase); if (q < (unsigned)sliceN) atomicAdd(&hist[q], 1);
        q = (unsigned)(d.z - nbase); if (q < (unsigned)sliceN) atomicAdd(&hist[q], 1);
        q = (unsigned)(d.w - nbase); if (q < (unsigned)sliceN) atomicAdd(&hist[q], 1);
    }
    if (threadIdx.x < (ne & 3)) {
        int d = dst[e0 + (n4 << 2) + threadIdx.x];
        unsigned q = (unsigned)(d - nbase);
        if (q < (unsigned)sliceN) atomicAdd(&hist[q], 1);
    }
    __syncthreads();
    for (int j = threadIdx.x; j < sliceN; j += 256) {
        int n = nbase + j;
        if (n < N) partial[(size_t)c * N + n] = hist[j];
    }
}

// ---- K2: deg = sum over chunks; dinv; per-block sum of deg ----
__launch_bounds__(256)
__global__ void k_degdinv(const int* __restrict__ partial, int* __restrict__ deg,
                          float* __restrict__ dinv, int* __restrict__ blocksum, int N) {
    int tid = threadIdx.x;
    int n = blockIdx.x * 256 + tid;
    int s = 0;
    if (n < N) {
        #pragma unroll
        for (int c = 0; c < NCHUNK; ++c) s += partial[(size_t)c * N + n];
        deg[n] = s;
        dinv[n] = rsqrtf((float)(s + 1));
    }
    __shared__ int sh[256];
    sh[tid] = s;
    __syncthreads();
    #pragma unroll
    for (int off = 128; off; off >>= 1) {
        if (tid < off) sh[tid] += sh[tid + off];
        __syncthreads();
    }
    if (tid == 0) blocksum[blockIdx.x] = sh[0];
}

// ---- K3: exclusive scan of block sums (nb <= 256), one block ----
__global__ void k_bscan(const int* __restrict__ blocksum, int* __restrict__ blockoff,
                        int* __restrict__ rowptrN, int nb) {
    __shared__ int sh[256];
    int tid = threadIdx.x;
    int v = (tid < nb) ? blocksum[tid] : 0;
    sh[tid] = v;
    __syncthreads();
    for (int off = 1; off < 256; off <<= 1) {
        int t = (tid >= off) ? sh[tid - off] : 0;
        __syncthreads();
        sh[tid] += t;
        __syncthreads();
    }
    if (tid < nb) blockoff[tid] = sh[tid] - v;   // exclusive
    if (tid == nb - 1) *rowptrN = sh[tid];       // total = E
}

// ---- K4: per-block LDS scan of deg -> rowptr; partial counts -> abs offsets ----
__launch_bounds__(256)
__global__ void k_offs(int* __restrict__ partial, const int* __restrict__ deg,
                       const int* __restrict__ blockoff, int* __restrict__ rowptr, int N) {
    int tid = threadIdx.x;
    int n = blockIdx.x * 256 + tid;
    int v = (n < N) ? deg[n] : 0;
    __shared__ int sh[256];
    sh[tid] = v;
    __syncthreads();
    for (int off = 1; off < 256; off <<= 1) {
        int t = (tid >= off) ? sh[tid - off] : 0;
        __syncthreads();
        sh[tid] += t;
        __syncthreads();
    }
    int run = blockoff[blockIdx.x] + sh[tid] - v;   // exclusive prefix
    if (n < N) {
        rowptr[n] = run;
        #pragma unroll
        for (int c = 0; c < NCHUNK; ++c) {
            size_t ix = (size_t)c * N + n;
            int t = partial[ix];
            partial[ix] = run;
            run += t;
        }
    }
}

// ---- K5: place edges into col via LDS cursors; rsum partials into offs (dead) ----
__launch_bounds__(256)
__global__ void k_place(const int* __restrict__ src, const int* __restrict__ dst,
                        const float* __restrict__ dinv, int* __restrict__ offs,
                        int* __restrict__ col, int N, int E, int chunkE, int sliceN) {
    int c = blockIdx.x >> 3, s = blockIdx.x & (NSLICE - 1);
    int nbase = s * sliceN;
    __shared__ int cur[SLICE_MAX];
    __shared__ float rs[SLICE_MAX];
    for (int j = threadIdx.x; j < sliceN; j += 256) {
        int n = nbase + j;
        cur[j] = (n < N) ? offs[(size_t)c * N + n] : 0;
        rs[j] = 0.f;
    }
    __syncthreads();
    int e0 = c * chunkE, e1 = min(e0 + chunkE, E);
    int ne = e1 - e0;
    const int4* s4 = (const int4*)(src + e0);
    const int4* d4 = (const int4*)(dst + e0);
    int n4 = ne >> 2;
    for (int i = threadIdx.x; i < n4; i += 256) {
        int4 sv = s4[i];
        int4 dv = d4[i];
        unsigned qd, qs;
        qd = (unsigned)(dv.x - nbase);
        if (qd < (unsigned)sliceN) { int p = atomicAdd(&cur[qd], 1); col[p] = sv.x; }
        qs = (unsigned)(sv.x - nbase);
        if (qs < (unsigned)sliceN) atomicAdd(&rs[qs], dinv[dv.x]);
        qd = (unsigned)(dv.y - nbase);
        if (qd < (unsigned)sliceN) { int p = atomicAdd(&cur[qd], 1); col[p] = sv.y; }
        qs = (unsigned)(sv.y - nbase);
        if (qs < (unsigned)sliceN) atomicAdd(&rs[qs], dinv[dv.y]);
        qd = (unsigned)(dv.z - nbase);
        if (qd < (unsigned)sliceN) { int p = atomicAdd(&cur[qd], 1); col[p] = sv.z; }
        qs = (unsigned)(sv.z - nbase);
        if (qs < (unsigned)sliceN) atomicAdd(&rs[qs], dinv[dv.z]);
        qd = (unsigned)(dv.w - nbase);
        if (qd < (unsigned)sliceN) { int p = atomicAdd(&cur[qd], 1); col[p] = sv.w; }
        qs = (unsigned)(sv.w - nbase);
        if (qs < (unsigned)sliceN) atomicAdd(&rs[qs], dinv[dv.w]);
    }
    if (threadIdx.x < (ne & 3)) {
        int e = e0 + (n4 << 2) + threadIdx.x;
        int sv = src[e], dv = dst[e];
        unsigned qd = (unsigned)(dv - nbase);
        if (qd < (unsigned)sliceN) { int p = atomicAdd(&cur[qd], 1); col[p] = sv; }
        unsigned qs = (unsigned)(sv - nbase);
        if (qs < (unsigned)sliceN) atomicAdd(&rs[qs], dinv[dv]);
    }
    __syncthreads();
    float* prs = (float*)offs;   // offs[c][this slice] dead after load -> reuse
    for (int j = threadIdx.x; j < sliceN; j += 256) {
        int n = nbase + j;
        if (n < N) prs[(size_t)c * N + n] = rs[j];
    }
}

// ---- K6: rsum = sum over chunk partials ----
__global__ void k_rsum(const float* __restrict__ prs, float* __restrict__ rsum, int N) {
    int n = blockIdx.x * 256 + threadIdx.x;
    if (n >= N) return;
    float s = 0.f;
    #pragma unroll
    for (int c = 0; c < NCHUNK; ++c) s += prs[(size_t)c * N + n];
    rsum[n] = s;
}

// ---- g = fp16( (x @ W1) * dinv[row] )   (M=50000, K=128, Ncols=96) ----
__launch_bounds__(256)
__global__ void k_gemm(const float* __restrict__ x, const float* __restrict__ W1,
                       const float* __restrict__ dinv, __half* __restrict__ g, int n) {
    __shared__ float Ws[128 * 96];
    int tid = threadIdx.x;
    {
        const float4* wsrc = (const float4*)W1;
        float4* wdst = (float4*)Ws;
        #pragma unroll
        for (int i = 0; i < 12; ++i) wdst[tid + 256 * i] = wsrc[tid + 256 * i];
    }
    __syncthreads();

    int tx = tid & 7;
    int ty = tid >> 3;
    int r0 = blockIdx.x * 64 + ty * 2;
    int r1 = r0 + 1;
    bool v0 = r0 < n, v1 = r1 < n;
    const float4* x0 = (const float4*)(x + (size_t)(v0 ? r0 : 0) * 128);
    const float4* x1 = (const float4*)(x + (size_t)(v1 ? r1 : 0) * 128);

    float4 acc[2][3];
    #pragma unroll
    for (int i = 0; i < 2; ++i)
        #pragma unroll
        for (int j = 0; j < 3; ++j) acc[i][j] = make_float4(0.f, 0.f, 0.f, 0.f);

    #pragma unroll 4
    for (int k4 = 0; k4 < 32; ++k4) {
        float4 a0 = x0[k4];
        float4 a1 = x1[k4];
        #pragma unroll
        for (int kk = 0; kk < 4; ++kk) {
            const float* wrow = &Ws[(k4 * 4 + kk) * 96 + tx * 12];
            float4 b0 = *(const float4*)(wrow);
            float4 b1 = *(const float4*)(wrow + 4);
            float4 b2 = *(const float4*)(wrow + 8);
            float av0 = (kk == 0) ? a0.x : (kk == 1) ? a0.y : (kk == 2) ? a0.z : a0.w;
            float av1 = (kk == 0) ? a1.x : (kk == 1) ? a1.y : (kk == 2) ? a1.z : a1.w;
            fma4(acc[0][0], av0, b0); fma4(acc[0][1], av0, b1); fma4(acc[0][2], av0, b2);
            fma4(acc[1][0], av1, b0); fma4(acc[1][1], av1, b1); fma4(acc[1][2], av1, b2);
        }
    }

    if (v0) {
        float dv = dinv[r0];
        uint2* o = (uint2*)(g + (size_t)r0 * 96) + tx * 3;
        float4 t;
        t = acc[0][0]; o[0] = make_uint2(f2h(t.x * dv, t.y * dv), f2h(t.z * dv, t.w * dv));
        t = acc[0][1]; o[1] = make_uint2(f2h(t.x * dv, t.y * dv), f2h(t.z * dv, t.w * dv));
        t = acc[0][2]; o[2] = make_uint2(f2h(t.x * dv, t.y * dv), f2h(t.z * dv, t.w * dv));
    }
    if (v1) {
        float dv = dinv[r1];
        uint2* o = (uint2*)(g + (size_t)r1 * 96) + tx * 3;
        float4 t;
        t = acc[1][0]; o[0] = make_uint2(f2h(t.x * dv, t.y * dv), f2h(t.z * dv, t.w * dv));
        t = acc[1][1]; o[1] = make_uint2(f2h(t.x * dv, t.y * dv), f2h(t.z * dv, t.w * dv));
        t = acc[1][2]; o[2] = make_uint2(f2h(t.x * dv, t.y * dv), f2h(t.z * dv, t.w * dv));
    }
}

// ---- per-node fp16 gather + fused bias/relu/c[d] weight + block partial of v ----
#define AGG_NODES 16
#define AGG_T (AGG_NODES * 24)
__launch_bounds__(AGG_T)
__global__ void k_agg(const uint2* __restrict__ g2, const int* __restrict__ col,
                      const int* __restrict__ rowptr, const float* __restrict__ dinv,
                      const float* __restrict__ rsum, const float* __restrict__ b1,
                      float* __restrict__ v_part, int n) {
    int tid = threadIdx.x;
    int nl = tid / 24;
    int ch = tid % 24;        // uint2 chunk of the 24-uint2 row (4 halves each)
    int d = blockIdx.x * AGG_NODES + nl;

    __shared__ float4 sh[AGG_NODES][24];

    float4 contrib = make_float4(0.f, 0.f, 0.f, 0.f);
    if (d < n) {
        float dd = dinv[d];
        int e0 = rowptr[d], e1 = rowptr[d + 1];
        float4 aA = make_float4(0.f, 0.f, 0.f, 0.f);
        float4 aB = make_float4(0.f, 0.f, 0.f, 0.f);
        int e = e0;
        for (; e + 4 <= e1; e += 4) {
            int s0 = col[e], s1 = col[e + 1], s2 = col[e + 2], s3 = col[e + 3];
            uint2 r0 = g2[(size_t)s0 * 24 + ch];
            uint2 r1 = g2[(size_t)s1 * 24 + ch];
            uint2 r2 = g2[(size_t)s2 * 24 + ch];
            uint2 r3 = g2[(size_t)s3 * 24 + ch];
            float2 f;
            f = h2f(r0.x); aA.x += f.x; aA.y += f.y;
            f = h2f(r0.y); aA.z += f.x; aA.w += f.y;
            f = h2f(r1.x); aB.x += f.x; aB.y += f.y;
            f = h2f(r1.y); aB.z += f.x; aB.w += f.y;
            f = h2f(r2.x); aA.x += f.x; aA.y += f.y;
            f = h2f(r2.y); aA.z += f.x; aA.w += f.y;
            f = h2f(r3.x); aB.x += f.x; aB.y += f.y;
            f = h2f(r3.y); aB.z += f.x; aB.w += f.y;
        }
        for (; e < e1; ++e) {
            uint2 r = g2[(size_t)col[e] * 24 + ch];
            float2 f;
            f = h2f(r.x); aA.x += f.x; aA.y += f.y;
            f = h2f(r.y); aA.z += f.x; aA.w += f.y;
        }
        uint2 rd = g2[(size_t)d * 24 + ch];   // analytic self-loop: g[d]*dinv[d]
        float2 fd0 = h2f(rd.x), fd1 = h2f(rd.y);
        float4 b1c = ((const float4*)b1)[ch];
        float cd = dd * (dd + rsum[d]);
        float hx = fmaxf(fmaf(dd, aA.x + aB.x + fd0.x, b1c.x), 0.f);
        float hy = fmaxf(fmaf(dd, aA.y + aB.y + fd0.y, b1c.y), 0.f);
        float hz = fmaxf(fmaf(dd, aA.z + aB.z + fd1.x, b1c.z), 0.f);
        float hw = fmaxf(fmaf(dd, aA.w + aB.w + fd1.y, b1c.w), 0.f);
        contrib = make_float4(cd * hx, cd * hy, cd * hz, cd * hw);
    }
    sh[nl][ch] = contrib;
    __syncthreads();
    #pragma unroll
    for (int off = 8; off >= 1; off >>= 1) {
        if (nl < off) {
            float4 a = sh[nl][ch];
            float4 b = sh[nl + off][ch];
            a.x += b.x; a.y += b.y; a.z += b.z; a.w += b.w;
            sh[nl][ch] = a;
        }
        __syncthreads();
    }
    if (tid < 24) {
        ((float4*)(v_part + (size_t)blockIdx.x * 96))[tid] = sh[0][tid];
    }
}

// ---- reduce v_part -> v[96] ----
__global__ void k_vred(const float* __restrict__ vp, float* __restrict__ v, int nb) {
    int j = blockIdx.x;
    float s = 0.f;
    for (int i = threadIdx.x; i < nb; i += 256) s += vp[(size_t)i * 96 + j];
    __shared__ float sh[256];
    sh[threadIdx.x] = s;
    __syncthreads();
    for (int off = 128; off; off >>= 1) {
        if (threadIdx.x < off) sh[threadIdx.x] += sh[threadIdx.x + off];
        __syncthreads();
    }
    if (threadIdx.x == 0) v[j] = sh[0];
}

// ---- mu = v@W_mu + N*b_mu ; logvar = v@W_lv + N*b_lv ----
__global__ void k_out(const float* __restrict__ v,
                      const float* __restrict__ Wmu, const float* __restrict__ bmu,
                      const float* __restrict__ Wlv, const float* __restrict__ blv,
                      float* __restrict__ out, float nN) {
    int tid = threadIdx.x;
    const float* W = (tid < 64) ? Wmu : Wlv;
    const float* b = (tid < 64) ? bmu : blv;
    int j = tid & 63;
    float s = 0.f;
    #pragma unroll
    for (int k = 0; k < 96; ++k) s = fmaf(v[k], W[k * 64 + j], s);
    out[tid] = s + nN * b[j];
}

extern "C" void kernel_launch(void* const* d_in, const int* in_sizes, int n_in,
                              void* d_out, int out_size, void* d_ws, size_t ws_size,
                              hipStream_t stream) {
    const float* x   = (const float*)d_in[0];
    const int*   ei  = (const int*)d_in[1];
    const float* W1  = (const float*)d_in[2];
    const float* b1  = (const float*)d_in[3];
    const float* Wmu = (const float*)d_in[4];
    const float* bmu = (const float*)d_in[5];
    const float* Wlv = (const float*)d_in[6];
    const float* blv = (const float*)d_in[7];
    float* out = (float*)d_out;

    const int N = in_sizes[0] / 128;   // 50000
    const int E = in_sizes[1] / 2;     // 800000
    const int* src = ei;
    const int* dst = ei + E;

    const int chunkE = (((E + NCHUNK - 1) / NCHUNK) + 3) & ~3;   // 12500
    const int sliceN = (N + NSLICE - 1) / NSLICE;                // 6250
    const int gN = (N + 255) / 256;                              // 196

    size_t off = 0;
    auto alloc = [&](size_t bytes) -> char* {
        off = (off + 255) & ~(size_t)255;
        char* p = (char*)d_ws + off;
        off += bytes;
        return p;
    };
    int*    partial  = (int*)alloc((size_t)NCHUNK * N * 4);   // counts->offs->rsum partials
    int*    rowptr   = (int*)alloc((size_t)(N + 1) * 4);
    int*    col      = (int*)alloc((size_t)E * 4);
    int*    deg      = (int*)alloc((size_t)N * 4);
    float*  dinv     = (float*)alloc((size_t)N * 4);
    float*  rsum     = (float*)alloc((size_t)N * 4);
    int*    blocksum = (int*)alloc((size_t)gN * 4);
    int*    blockoff = (int*)alloc((size_t)gN * 4);
    __half* g        = (__half*)alloc((size_t)N * 96 * 2);
    const int nAggBlocks = (N + AGG_NODES - 1) / AGG_NODES;
    float*  v_part   = (float*)alloc((size_t)nAggBlocks * 96 * 4);
    float*  v        = (float*)alloc(96 * 4);

    k_count<<<NCHUNK * NSLICE, 256, 0, stream>>>(dst, partial, N, E, chunkE, sliceN);
    k_degdinv<<<gN, 256, 0, stream>>>(partial, deg, dinv, blocksum, N);
    k_bscan<<<1, 256, 0, stream>>>(blocksum, blockoff, rowptr + N, gN);
    k_offs<<<gN, 256, 0, stream>>>(partial, deg, blockoff, rowptr, N);
    k_place<<<NCHUNK * NSLICE, 256, 0, stream>>>(src, dst, dinv, partial, col, N, E, chunkE, sliceN);
    k_rsum<<<gN, 256, 0, stream>>>((const float*)partial, rsum, N);
    k_gemm<<<(N + 63) / 64, 256, 0, stream>>>(x, W1, dinv, g, N);
    k_agg<<<nAggBlocks, AGG_T, 0, stream>>>((const uint2*)g, col, rowptr, dinv,
                                            rsum, b1, v_part, N);
    k_vred<<<96, 256, 0, stream>>>(v_part, v, nAggBlocks);
    k_out<<<1, 128, 0, stream>>>(v, Wmu, bmu, Wlv, blv, out, (float)N);
}

// Round 6
// 138.572 us; speedup vs baseline: 1.9619x; 1.0374x over previous
//
#include <hip/hip_runtime.h>
#include <hip/hip_fp16.h>

// GCN encoder, N=50000, E=800000, 128 -> 96 (relu) -> sum-pooled 64+64.
// Sum-pooled layer 2: out = (sum_u c[u]*h[u]) @ W + N*b,
//   c[u] = dinv[u]*(dinv[u] + rsum[u]),  rsum[u] = sum_{e: src=u} dinv[dst_e].
// Layer 1 with g[u] = (xW1)[u]*dinv[u]:
//   h[d] = relu( dinv[d]*(sum_{e->d} g[src] + g[d]) + b1 )
// g stored FP16. CSR build = counting sort (32 chunks x 8 slices), zero device
// atomics, hierarchical scan. rsum+cfac fused into k_gemm (9 kernels total).

#define NTHREADS 256
#define NCHUNK 32
#define NSLICE 8
#define SLICE_MAX 6272   // LDS hist capacity; N <= 8*6272

__device__ inline void fma4(float4& c, float a, const float4& b) {
    c.x = fmaf(a, b.x, c.x); c.y = fmaf(a, b.y, c.y);
    c.z = fmaf(a, b.z, c.z); c.w = fmaf(a, b.w, c.w);
}

__device__ inline unsigned f2h(float a, float b) {
    __half2 h = __floats2half2_rn(a, b);
    return *reinterpret_cast<unsigned*>(&h);
}
__device__ inline float2 h2f(unsigned u) {
    __half2 h = *reinterpret_cast<__half2*>(&u);
    return __half22float2(h);
}

// ---- K1: per-(chunk,slice) dst histogram via LDS ----
__launch_bounds__(256)
__global__ void k_count(const int* __restrict__ dst, int* __restrict__ partial,
                        int N, int E, int chunkE, int sliceN) {
    int c = blockIdx.x >> 3, s = blockIdx.x & (NSLICE - 1);
    int nbase = s * sliceN;
    __shared__ int hist[SLICE_MAX];
    for (int j = threadIdx.x; j < sliceN; j += 256) hist[j] = 0;
    __syncthreads();
    int e0 = c * chunkE, e1 = min(e0 + chunkE, E);
    int ne = e1 - e0;
    const int4* d4 = (const int4*)(dst + e0);
    int n4 = ne >> 2;
    for (int i = threadIdx.x; i < n4; i += 256) {
        int4 d = d4[i];
        unsigned q;
        q = (unsigned)(d.x - nbase); if (q < (unsigned)sliceN) atomicAdd(&hist[q], 1);
        q = (unsigned)(d.y - nbase); if (q < (unsigned)sliceN) atomicAdd(&hist[q], 1);
        q = (unsigned)(d.z - nbase); if (q < (unsigned)sliceN) atomicAdd(&hist[q], 1);
        q = (unsigned)(d.w - nbase); if (q < (unsigned)sliceN) atomicAdd(&hist[q], 1);
    }
    if (threadIdx.x < (ne & 3)) {
        int d = dst[e0 + (n4 << 2) + threadIdx.x];
        unsigned q = (unsigned)(d - nbase);
        if (q < (unsigned)sliceN) atomicAdd(&hist[q], 1);
    }
    __syncthreads();
    for (int j = threadIdx.x; j < sliceN; j += 256) {
        int n = nbase + j;
        if (n < N) partial[(size_t)c * N + n] = hist[j];
    }
}

// ---- K2: deg = sum over chunks; dinv; per-block sum of deg ----
__launch_bounds__(256)
__global__ void k_degdinv(const int* __restrict__ partial, int* __restrict__ deg,
                          float* __restrict__ dinv, int* __restrict__ blocksum, int N) {
    int tid = threadIdx.x;
    int n = blockIdx.x * 256 + tid;
    int s = 0;
    if (n < N) {
        #pragma unroll
        for (int c = 0; c < NCHUNK; ++c) s += partial[(size_t)c * N + n];
        deg[n] = s;
        dinv[n] = rsqrtf((float)(s + 1));
    }
    __shared__ int sh[256];
    sh[tid] = s;
    __syncthreads();
    #pragma unroll
    for (int off = 128; off; off >>= 1) {
        if (tid < off) sh[tid] += sh[tid + off];
        __syncthreads();
    }
    if (tid == 0) blocksum[blockIdx.x] = sh[0];
}

// ---- K3: exclusive scan of block sums (nb <= 256), one block ----
__global__ void k_bscan(const int* __restrict__ blocksum, int* __restrict__ blockoff,
                        int* __restrict__ rowptrN, int nb) {
    __shared__ int sh[256];
    int tid = threadIdx.x;
    int v = (tid < nb) ? blocksum[tid] : 0;
    sh[tid] = v;
    __syncthreads();
    for (int off = 1; off < 256; off <<= 1) {
        int t = (tid >= off) ? sh[tid - off] : 0;
        __syncthreads();
        sh[tid] += t;
        __syncthreads();
    }
    if (tid < nb) blockoff[tid] = sh[tid] - v;   // exclusive
    if (tid == nb - 1) *rowptrN = sh[tid];       // total = E
}

// ---- K4: per-block LDS scan of deg -> rowptr; partial counts -> abs offsets ----
__launch_bounds__(256)
__global__ void k_offs(int* __restrict__ partial, const int* __restrict__ deg,
                       const int* __restrict__ blockoff, int* __restrict__ rowptr, int N) {
    int tid = threadIdx.x;
    int n = blockIdx.x * 256 + tid;
    int v = (n < N) ? deg[n] : 0;
    __shared__ int sh[256];
    sh[tid] = v;
    __syncthreads();
    for (int off = 1; off < 256; off <<= 1) {
        int t = (tid >= off) ? sh[tid - off] : 0;
        __syncthreads();
        sh[tid] += t;
        __syncthreads();
    }
    int run = blockoff[blockIdx.x] + sh[tid] - v;   // exclusive prefix
    if (n < N) {
        rowptr[n] = run;
        #pragma unroll
        for (int c = 0; c < NCHUNK; ++c) {
            size_t ix = (size_t)c * N + n;
            int t = partial[ix];
            partial[ix] = run;
            run += t;
        }
    }
}

// ---- K5: place edges into col via LDS cursors; rsum partials into offs (dead) ----
__launch_bounds__(256)
__global__ void k_place(const int* __restrict__ src, const int* __restrict__ dst,
                        const float* __restrict__ dinv, int* __restrict__ offs,
                        int* __restrict__ col, int N, int E, int chunkE, int sliceN) {
    int c = blockIdx.x >> 3, s = blockIdx.x & (NSLICE - 1);
    int nbase = s * sliceN;
    __shared__ int cur[SLICE_MAX];
    __shared__ float rs[SLICE_MAX];
    for (int j = threadIdx.x; j < sliceN; j += 256) {
        int n = nbase + j;
        cur[j] = (n < N) ? offs[(size_t)c * N + n] : 0;
        rs[j] = 0.f;
    }
    __syncthreads();
    int e0 = c * chunkE, e1 = min(e0 + chunkE, E);
    int ne = e1 - e0;
    const int4* s4 = (const int4*)(src + e0);
    const int4* d4 = (const int4*)(dst + e0);
    int n4 = ne >> 2;
    for (int i = threadIdx.x; i < n4; i += 256) {
        int4 sv = s4[i];
        int4 dv = d4[i];
        unsigned qd, qs;
        qd = (unsigned)(dv.x - nbase);
        if (qd < (unsigned)sliceN) { int p = atomicAdd(&cur[qd], 1); col[p] = sv.x; }
        qs = (unsigned)(sv.x - nbase);
        if (qs < (unsigned)sliceN) atomicAdd(&rs[qs], dinv[dv.x]);
        qd = (unsigned)(dv.y - nbase);
        if (qd < (unsigned)sliceN) { int p = atomicAdd(&cur[qd], 1); col[p] = sv.y; }
        qs = (unsigned)(sv.y - nbase);
        if (qs < (unsigned)sliceN) atomicAdd(&rs[qs], dinv[dv.y]);
        qd = (unsigned)(dv.z - nbase);
        if (qd < (unsigned)sliceN) { int p = atomicAdd(&cur[qd], 1); col[p] = sv.z; }
        qs = (unsigned)(sv.z - nbase);
        if (qs < (unsigned)sliceN) atomicAdd(&rs[qs], dinv[dv.z]);
        qd = (unsigned)(dv.w - nbase);
        if (qd < (unsigned)sliceN) { int p = atomicAdd(&cur[qd], 1); col[p] = sv.w; }
        qs = (unsigned)(sv.w - nbase);
        if (qs < (unsigned)sliceN) atomicAdd(&rs[qs], dinv[dv.w]);
    }
    if (threadIdx.x < (ne & 3)) {
        int e = e0 + (n4 << 2) + threadIdx.x;
        int sv = src[e], dv = dst[e];
        unsigned qd = (unsigned)(dv - nbase);
        if (qd < (unsigned)sliceN) { int p = atomicAdd(&cur[qd], 1); col[p] = sv; }
        unsigned qs = (unsigned)(sv - nbase);
        if (qs < (unsigned)sliceN) atomicAdd(&rs[qs], dinv[dv]);
    }
    __syncthreads();
    float* prs = (float*)offs;   // offs[c][this slice] dead after load -> reuse
    for (int j = threadIdx.x; j < sliceN; j += 256) {
        int n = nbase + j;
        if (n < N) prs[(size_t)c * N + n] = rs[j];
    }
}

// ---- K6: g = fp16((x @ W1)*dinv[row]); fused cfac = dinv*(dinv+rsum) ----
// 256 thr, tile 128 rows x 96 cols, 4 rows/thread (halves LDS read traffic).
__launch_bounds__(256)
__global__ void k_gemm(const float* __restrict__ x, const float* __restrict__ W1,
                       const float* __restrict__ dinv, const float* __restrict__ prs,
                       float* __restrict__ cfac, __half* __restrict__ g, int n) {
    __shared__ float Ws[128 * 96];
    int tid = threadIdx.x;
    {
        const float4* wsrc = (const float4*)W1;
        float4* wdst = (float4*)Ws;
        #pragma unroll
        for (int i = 0; i < 12; ++i) wdst[tid + 256 * i] = wsrc[tid + 256 * i];
    }
    // fused rsum->cfac for this block's 128 rows (register-only, overlaps staging)
    {
        int r = blockIdx.x * 128 + tid;
        if (tid < 128 && r < n) {
            float s = 0.f;
            #pragma unroll
            for (int c = 0; c < NCHUNK; ++c) s += prs[(size_t)c * n + r];
            float dv = dinv[r];
            cfac[r] = dv * (dv + s);
        }
    }
    __syncthreads();

    int tx = tid & 7;          // 8 col groups of 12
    int ty = tid >> 3;         // 32 row quads
    int rbase = blockIdx.x * 128 + ty * 4;
    const float4* xp[4];
    bool vr[4];
    #pragma unroll
    for (int i = 0; i < 4; ++i) {
        int r = rbase + i;
        vr[i] = r < n;
        xp[i] = (const float4*)(x + (size_t)(vr[i] ? r : 0) * 128);
    }

    float4 acc[4][3];
    #pragma unroll
    for (int i = 0; i < 4; ++i)
        #pragma unroll
        for (int j = 0; j < 3; ++j) acc[i][j] = make_float4(0.f, 0.f, 0.f, 0.f);

    #pragma unroll 2
    for (int k4 = 0; k4 < 32; ++k4) {
        float4 a0 = xp[0][k4];
        float4 a1 = xp[1][k4];
        float4 a2 = xp[2][k4];
        float4 a3 = xp[3][k4];
        #pragma unroll
        for (int kk = 0; kk < 4; ++kk) {
            const float* wrow = &Ws[(k4 * 4 + kk) * 96 + tx * 12];
            float4 b0 = *(const float4*)(wrow);
            float4 b1 = *(const float4*)(wrow + 4);
            float4 b2 = *(const float4*)(wrow + 8);
            float av0 = (kk == 0) ? a0.x : (kk == 1) ? a0.y : (kk == 2) ? a0.z : a0.w;
            float av1 = (kk == 0) ? a1.x : (kk == 1) ? a1.y : (kk == 2) ? a1.z : a1.w;
            float av2 = (kk == 0) ? a2.x : (kk == 1) ? a2.y : (kk == 2) ? a2.z : a2.w;
            float av3 = (kk == 0) ? a3.x : (kk == 1) ? a3.y : (kk == 2) ? a3.z : a3.w;
            fma4(acc[0][0], av0, b0); fma4(acc[0][1], av0, b1); fma4(acc[0][2], av0, b2);
            fma4(acc[1][0], av1, b0); fma4(acc[1][1], av1, b1); fma4(acc[1][2], av1, b2);
            fma4(acc[2][0], av2, b0); fma4(acc[2][1], av2, b1); fma4(acc[2][2], av2, b2);
            fma4(acc[3][0], av3, b0); fma4(acc[3][1], av3, b1); fma4(acc[3][2], av3, b2);
        }
    }

    #pragma unroll
    for (int i = 0; i < 4; ++i) {
        if (!vr[i]) continue;
        int r = rbase + i;
        float dv = dinv[r];
        uint2* o = (uint2*)(g + (size_t)r * 96) + tx * 3;
        float4 t;
        t = acc[i][0]; o[0] = make_uint2(f2h(t.x * dv, t.y * dv), f2h(t.z * dv, t.w * dv));
        t = acc[i][1]; o[1] = make_uint2(f2h(t.x * dv, t.y * dv), f2h(t.z * dv, t.w * dv));
        t = acc[i][2]; o[2] = make_uint2(f2h(t.x * dv, t.y * dv), f2h(t.z * dv, t.w * dv));
    }
}

// ---- per-node fp16 gather + fused bias/relu/cfac weight + block partial of v ----
#define AGG_NODES 16
#define AGG_T (AGG_NODES * 24)
__launch_bounds__(AGG_T)
__global__ void k_agg(const uint2* __restrict__ g2, const int* __restrict__ col,
                      const int* __restrict__ rowptr, const float* __restrict__ dinv,
                      const float* __restrict__ cfac, const float* __restrict__ b1,
                      float* __restrict__ v_part, int n) {
    int tid = threadIdx.x;
    int nl = tid / 24;
    int ch = tid % 24;        // uint2 chunk of the 24-uint2 row (4 halves each)
    int d = blockIdx.x * AGG_NODES + nl;

    __shared__ float4 sh[AGG_NODES][24];

    float4 contrib = make_float4(0.f, 0.f, 0.f, 0.f);
    if (d < n) {
        float dd = dinv[d];
        int e0 = rowptr[d], e1 = rowptr[d + 1];
        float4 aA = make_float4(0.f, 0.f, 0.f, 0.f);
        float4 aB = make_float4(0.f, 0.f, 0.f, 0.f);
        int e = e0;
        for (; e + 4 <= e1; e += 4) {
            int s0 = col[e], s1 = col[e + 1], s2 = col[e + 2], s3 = col[e + 3];
            uint2 r0 = g2[(size_t)s0 * 24 + ch];
            uint2 r1 = g2[(size_t)s1 * 24 + ch];
            uint2 r2 = g2[(size_t)s2 * 24 + ch];
            uint2 r3 = g2[(size_t)s3 * 24 + ch];
            float2 f;
            f = h2f(r0.x); aA.x += f.x; aA.y += f.y;
            f = h2f(r0.y); aA.z += f.x; aA.w += f.y;
            f = h2f(r1.x); aB.x += f.x; aB.y += f.y;
            f = h2f(r1.y); aB.z += f.x; aB.w += f.y;
            f = h2f(r2.x); aA.x += f.x; aA.y += f.y;
            f = h2f(r2.y); aA.z += f.x; aA.w += f.y;
            f = h2f(r3.x); aB.x += f.x; aB.y += f.y;
            f = h2f(r3.y); aB.z += f.x; aB.w += f.y;
        }
        for (; e < e1; ++e) {
            uint2 r = g2[(size_t)col[e] * 24 + ch];
            float2 f;
            f = h2f(r.x); aA.x += f.x; aA.y += f.y;
            f = h2f(r.y); aA.z += f.x; aA.w += f.y;
        }
        uint2 rd = g2[(size_t)d * 24 + ch];   // analytic self-loop: g[d]*dinv[d]
        float2 fd0 = h2f(rd.x), fd1 = h2f(rd.y);
        float4 b1c = ((const float4*)b1)[ch];
        float cd = cfac[d];
        float hx = fmaxf(fmaf(dd, aA.x + aB.x + fd0.x, b1c.x), 0.f);
        float hy = fmaxf(fmaf(dd, aA.y + aB.y + fd0.y, b1c.y), 0.f);
        float hz = fmaxf(fmaf(dd, aA.z + aB.z + fd1.x, b1c.z), 0.f);
        float hw = fmaxf(fmaf(dd, aA.w + aB.w + fd1.y, b1c.w), 0.f);
        contrib = make_float4(cd * hx, cd * hy, cd * hz, cd * hw);
    }
    sh[nl][ch] = contrib;
    __syncthreads();
    #pragma unroll
    for (int off = 8; off >= 1; off >>= 1) {
        if (nl < off) {
            float4 a = sh[nl][ch];
            float4 b = sh[nl + off][ch];
            a.x += b.x; a.y += b.y; a.z += b.z; a.w += b.w;
            sh[nl][ch] = a;
        }
        __syncthreads();
    }
    if (tid < 24) {
        ((float4*)(v_part + (size_t)blockIdx.x * 96))[tid] = sh[0][tid];
    }
}

// ---- reduce v_part -> v[96] ----
__global__ void k_vred(const float* __restrict__ vp, float* __restrict__ v, int nb) {
    int j = blockIdx.x;
    float s = 0.f;
    for (int i = threadIdx.x; i < nb; i += 256) s += vp[(size_t)i * 96 + j];
    __shared__ float sh[256];
    sh[threadIdx.x] = s;
    __syncthreads();
    for (int off = 128; off; off >>= 1) {
        if (threadIdx.x < off) sh[threadIdx.x] += sh[threadIdx.x + off];
        __syncthreads();
    }
    if (threadIdx.x == 0) v[j] = sh[0];
}

// ---- mu = v@W_mu + N*b_mu ; logvar = v@W_lv + N*b_lv ----
__global__ void k_out(const float* __restrict__ v,
                      const float* __restrict__ Wmu, const float* __restrict__ bmu,
                      const float* __restrict__ Wlv, const float* __restrict__ blv,
                      float* __restrict__ out, float nN) {
    int tid = threadIdx.x;
    const float* W = (tid < 64) ? Wmu : Wlv;
    const float* b = (tid < 64) ? bmu : blv;
    int j = tid & 63;
    float s = 0.f;
    #pragma unroll
    for (int k = 0; k < 96; ++k) s = fmaf(v[k], W[k * 64 + j], s);
    out[tid] = s + nN * b[j];
}

extern "C" void kernel_launch(void* const* d_in, const int* in_sizes, int n_in,
                              void* d_out, int out_size, void* d_ws, size_t ws_size,
                              hipStream_t stream) {
    const float* x   = (const float*)d_in[0];
    const int*   ei  = (const int*)d_in[1];
    const float* W1  = (const float*)d_in[2];
    const float* b1  = (const float*)d_in[3];
    const float* Wmu = (const float*)d_in[4];
    const float* bmu = (const float*)d_in[5];
    const float* Wlv = (const float*)d_in[6];
    const float* blv = (const float*)d_in[7];
    float* out = (float*)d_out;

    const int N = in_sizes[0] / 128;   // 50000
    const int E = in_sizes[1] / 2;     // 800000
    const int* src = ei;
    const int* dst = ei + E;

    const int chunkE = (((E + NCHUNK - 1) / NCHUNK) + 3) & ~3;   // 25000
    const int sliceN = (N + NSLICE - 1) / NSLICE;                // 6250
    const int gN = (N + 255) / 256;                              // 196

    size_t off = 0;
    auto alloc = [&](size_t bytes) -> char* {
        off = (off + 255) & ~(size_t)255;
        char* p = (char*)d_ws + off;
        off += bytes;
        return p;
    };
    int*    partial  = (int*)alloc((size_t)NCHUNK * N * 4);   // counts->offs->rsum partials
    int*    rowptr   = (int*)alloc((size_t)(N + 1) * 4);
    int*    col      = (int*)alloc((size_t)E * 4);
    int*    deg      = (int*)alloc((size_t)N * 4);
    float*  dinv     = (float*)alloc((size_t)N * 4);
    float*  cfac     = (float*)alloc((size_t)N * 4);
    int*    blocksum = (int*)alloc((size_t)gN * 4);
    int*    blockoff = (int*)alloc((size_t)gN * 4);
    __half* g        = (__half*)alloc((size_t)N * 96 * 2);
    const int nAggBlocks = (N + AGG_NODES - 1) / AGG_NODES;
    float*  v_part   = (float*)alloc((size_t)nAggBlocks * 96 * 4);
    float*  v        = (float*)alloc(96 * 4);

    k_count<<<NCHUNK * NSLICE, 256, 0, stream>>>(dst, partial, N, E, chunkE, sliceN);
    k_degdinv<<<gN, 256, 0, stream>>>(partial, deg, dinv, blocksum, N);
    k_bscan<<<1, 256, 0, stream>>>(blocksum, blockoff, rowptr + N, gN);
    k_offs<<<gN, 256, 0, stream>>>(partial, deg, blockoff, rowptr, N);
    k_place<<<NCHUNK * NSLICE, 256, 0, stream>>>(src, dst, dinv, partial, col, N, E, chunkE, sliceN);
    k_gemm<<<(N + 127) / 128, 256, 0, stream>>>(x, W1, dinv, (const float*)partial, cfac, g, N);
    k_agg<<<nAggBlocks, AGG_T, 0, stream>>>((const uint2*)g, col, rowptr, dinv,
                                            cfac, b1, v_part, N);
    k_vred<<<96, 256, 0, stream>>>(v_part, v, nAggBlocks);
    k_out<<<1, 128, 0, stream>>>(v, Wmu, bmu, Wlv, blv, out, (float)N);
}

// Round 7
// 100.757 us; speedup vs baseline: 2.6983x; 1.3753x over previous
//
#include <hip/hip_runtime.h>
#include <hip/hip_fp16.h>

// GCN encoder, N=50000, E=800000, 128 -> 96 (relu) -> sum-pooled 64+64.
// Sum-pooled layer 2: out = (sum_u c[u]*h[u]) @ W + N*b,
//   c[u] = dinv[u]*(dinv[u] + rsum[u]),  rsum[u] = sum_{e: src=u} dinv[dst_e].
// Layer 1 with g[u] = (xW1)[u]*dinv[u]:
//   h[d] = relu( dinv[d]*(sum_{e->d} g[src] + g[d]) + b1 )
// g stored FP16. CSR build = counting sort (32 chunks x 8 slices), zero device
// atomics. count/place: 1024-thr blocks (16 waves/CU, was 4) and chunk-major
// block indexing so a chunk's 8 slice-blocks share one XCD's L2.

#define NTHREADS 256
#define NCHUNK 32
#define LOG_NCHUNK 5
#define NSLICE 8
#define SLICE_MAX 6272   // LDS hist capacity; N <= 8*6272
#define SORT_T 1024      // threads for count/place

__device__ inline void fma4(float4& c, float a, const float4& b) {
    c.x = fmaf(a, b.x, c.x); c.y = fmaf(a, b.y, c.y);
    c.z = fmaf(a, b.z, c.z); c.w = fmaf(a, b.w, c.w);
}

__device__ inline unsigned f2h(float a, float b) {
    __half2 h = __floats2half2_rn(a, b);
    return *reinterpret_cast<unsigned*>(&h);
}
__device__ inline float2 h2f(unsigned u) {
    __half2 h = *reinterpret_cast<__half2*>(&u);
    return __half22float2(h);
}

// ---- K1: per-(chunk,slice) dst histogram via LDS ----
// blockIdx: c = bid & 31 (chunk-major) so same-chunk blocks hit one XCD.
__launch_bounds__(SORT_T)
__global__ void k_count(const int* __restrict__ dst, int* __restrict__ partial,
                        int N, int E, int chunkE, int sliceN) {
    int c = blockIdx.x & (NCHUNK - 1), s = blockIdx.x >> LOG_NCHUNK;
    int nbase = s * sliceN;
    __shared__ int hist[SLICE_MAX];
    for (int j = threadIdx.x; j < sliceN; j += SORT_T) hist[j] = 0;
    __syncthreads();
    int e0 = c * chunkE, e1 = min(e0 + chunkE, E);
    int ne = e1 - e0;
    const int4* d4 = (const int4*)(dst + e0);
    int n4 = ne >> 2;
    for (int i = threadIdx.x; i < n4; i += SORT_T) {
        int4 d = d4[i];
        unsigned q;
        q = (unsigned)(d.x - nbase); if (q < (unsigned)sliceN) atomicAdd(&hist[q], 1);
        q = (unsigned)(d.y - nbase); if (q < (unsigned)sliceN) atomicAdd(&hist[q], 1);
        q = (unsigned)(d.z - nbase); if (q < (unsigned)sliceN) atomicAdd(&hist[q], 1);
        q = (unsigned)(d.w - nbase); if (q < (unsigned)sliceN) atomicAdd(&hist[q], 1);
    }
    if (threadIdx.x < (ne & 3)) {
        int d = dst[e0 + (n4 << 2) + threadIdx.x];
        unsigned q = (unsigned)(d - nbase);
        if (q < (unsigned)sliceN) atomicAdd(&hist[q], 1);
    }
    __syncthreads();
    for (int j = threadIdx.x; j < sliceN; j += SORT_T) {
        int n = nbase + j;
        if (n < N) partial[(size_t)c * N + n] = hist[j];
    }
}

// ---- K2: deg = sum over chunks; dinv; per-block sum of deg ----
__launch_bounds__(256)
__global__ void k_degdinv(const int* __restrict__ partial, int* __restrict__ deg,
                          float* __restrict__ dinv, int* __restrict__ blocksum, int N) {
    int tid = threadIdx.x;
    int n = blockIdx.x * 256 + tid;
    int s = 0;
    if (n < N) {
        #pragma unroll
        for (int c = 0; c < NCHUNK; ++c) s += partial[(size_t)c * N + n];
        deg[n] = s;
        dinv[n] = rsqrtf((float)(s + 1));
    }
    __shared__ int sh[256];
    sh[tid] = s;
    __syncthreads();
    #pragma unroll
    for (int off = 128; off; off >>= 1) {
        if (tid < off) sh[tid] += sh[tid + off];
        __syncthreads();
    }
    if (tid == 0) blocksum[blockIdx.x] = sh[0];
}

// ---- K3: exclusive scan of block sums (nb <= 256), one block ----
__global__ void k_bscan(const int* __restrict__ blocksum, int* __restrict__ blockoff,
                        int* __restrict__ rowptrN, int nb) {
    __shared__ int sh[256];
    int tid = threadIdx.x;
    int v = (tid < nb) ? blocksum[tid] : 0;
    sh[tid] = v;
    __syncthreads();
    for (int off = 1; off < 256; off <<= 1) {
        int t = (tid >= off) ? sh[tid - off] : 0;
        __syncthreads();
        sh[tid] += t;
        __syncthreads();
    }
    if (tid < nb) blockoff[tid] = sh[tid] - v;   // exclusive
    if (tid == nb - 1) *rowptrN = sh[tid];       // total = E
}

// ---- K4: per-block LDS scan of deg -> rowptr; partial counts -> abs offsets ----
__launch_bounds__(256)
__global__ void k_offs(int* __restrict__ partial, const int* __restrict__ deg,
                       const int* __restrict__ blockoff, int* __restrict__ rowptr, int N) {
    int tid = threadIdx.x;
    int n = blockIdx.x * 256 + tid;
    int v = (n < N) ? deg[n] : 0;
    __shared__ int sh[256];
    sh[tid] = v;
    __syncthreads();
    for (int off = 1; off < 256; off <<= 1) {
        int t = (tid >= off) ? sh[tid - off] : 0;
        __syncthreads();
        sh[tid] += t;
        __syncthreads();
    }
    int run = blockoff[blockIdx.x] + sh[tid] - v;   // exclusive prefix
    if (n < N) {
        rowptr[n] = run;
        #pragma unroll
        for (int c = 0; c < NCHUNK; ++c) {
            size_t ix = (size_t)c * N + n;
            int t = partial[ix];
            partial[ix] = run;
            run += t;
        }
    }
}

// ---- K5: place edges into col via LDS cursors; rsum partials into offs (dead) ----
__launch_bounds__(SORT_T)
__global__ void k_place(const int* __restrict__ src, const int* __restrict__ dst,
                        const float* __restrict__ dinv, int* __restrict__ offs,
                        int* __restrict__ col, int N, int E, int chunkE, int sliceN) {
    int c = blockIdx.x & (NCHUNK - 1), s = blockIdx.x >> LOG_NCHUNK;
    int nbase = s * sliceN;
    __shared__ int cur[SLICE_MAX];
    __shared__ float rs[SLICE_MAX];
    for (int j = threadIdx.x; j < sliceN; j += SORT_T) {
        int n = nbase + j;
        cur[j] = (n < N) ? offs[(size_t)c * N + n] : 0;
        rs[j] = 0.f;
    }
    __syncthreads();
    int e0 = c * chunkE, e1 = min(e0 + chunkE, E);
    int ne = e1 - e0;
    const int4* s4 = (const int4*)(src + e0);
    const int4* d4 = (const int4*)(dst + e0);
    int n4 = ne >> 2;
    for (int i = threadIdx.x; i < n4; i += SORT_T) {
        int4 sv = s4[i];
        int4 dv = d4[i];
        unsigned qd, qs;
        qd = (unsigned)(dv.x - nbase);
        if (qd < (unsigned)sliceN) { int p = atomicAdd(&cur[qd], 1); col[p] = sv.x; }
        qs = (unsigned)(sv.x - nbase);
        if (qs < (unsigned)sliceN) atomicAdd(&rs[qs], dinv[dv.x]);
        qd = (unsigned)(dv.y - nbase);
        if (qd < (unsigned)sliceN) { int p = atomicAdd(&cur[qd], 1); col[p] = sv.y; }
        qs = (unsigned)(sv.y - nbase);
        if (qs < (unsigned)sliceN) atomicAdd(&rs[qs], dinv[dv.y]);
        qd = (unsigned)(dv.z - nbase);
        if (qd < (unsigned)sliceN) { int p = atomicAdd(&cur[qd], 1); col[p] = sv.z; }
        qs = (unsigned)(sv.z - nbase);
        if (qs < (unsigned)sliceN) atomicAdd(&rs[qs], dinv[dv.z]);
        qd = (unsigned)(dv.w - nbase);
        if (qd < (unsigned)sliceN) { int p = atomicAdd(&cur[qd], 1); col[p] = sv.w; }
        qs = (unsigned)(sv.w - nbase);
        if (qs < (unsigned)sliceN) atomicAdd(&rs[qs], dinv[dv.w]);
    }
    if (threadIdx.x < (ne & 3)) {
        int e = e0 + (n4 << 2) + threadIdx.x;
        int sv = src[e], dv = dst[e];
        unsigned qd = (unsigned)(dv - nbase);
        if (qd < (unsigned)sliceN) { int p = atomicAdd(&cur[qd], 1); col[p] = sv; }
        unsigned qs = (unsigned)(sv - nbase);
        if (qs < (unsigned)sliceN) atomicAdd(&rs[qs], dinv[dv]);
    }
    __syncthreads();
    float* prs = (float*)offs;   // offs[c][this slice] dead after load -> reuse
    for (int j = threadIdx.x; j < sliceN; j += SORT_T) {
        int n = nbase + j;
        if (n < N) prs[(size_t)c * N + n] = rs[j];
    }
}

// ---- K6: g = fp16((x @ W1)*dinv[row]); fused cfac = dinv*(dinv+rsum) ----
__launch_bounds__(256)
__global__ void k_gemm(const float* __restrict__ x, const float* __restrict__ W1,
                       const float* __restrict__ dinv, const float* __restrict__ prs,
                       float* __restrict__ cfac, __half* __restrict__ g, int n) {
    __shared__ float Ws[128 * 96];
    int tid = threadIdx.x;
    {
        const float4* wsrc = (const float4*)W1;
        float4* wdst = (float4*)Ws;
        #pragma unroll
        for (int i = 0; i < 12; ++i) wdst[tid + 256 * i] = wsrc[tid + 256 * i];
    }
    // fused rsum->cfac for this block's 128 rows (register-only, overlaps staging)
    {
        int r = blockIdx.x * 128 + tid;
        if (tid < 128 && r < n) {
            float s = 0.f;
            #pragma unroll
            for (int c = 0; c < NCHUNK; ++c) s += prs[(size_t)c * n + r];
            float dv = dinv[r];
            cfac[r] = dv * (dv + s);
        }
    }
    __syncthreads();

    int tx = tid & 7;          // 8 col groups of 12
    int ty = tid >> 3;         // 32 row quads
    int rbase = blockIdx.x * 128 + ty * 4;
    const float4* xp[4];
    bool vr[4];
    #pragma unroll
    for (int i = 0; i < 4; ++i) {
        int r = rbase + i;
        vr[i] = r < n;
        xp[i] = (const float4*)(x + (size_t)(vr[i] ? r : 0) * 128);
    }

    float4 acc[4][3];
    #pragma unroll
    for (int i = 0; i < 4; ++i)
        #pragma unroll
        for (int j = 0; j < 3; ++j) acc[i][j] = make_float4(0.f, 0.f, 0.f, 0.f);

    #pragma unroll 2
    for (int k4 = 0; k4 < 32; ++k4) {
        float4 a0 = xp[0][k4];
        float4 a1 = xp[1][k4];
        float4 a2 = xp[2][k4];
        float4 a3 = xp[3][k4];
        #pragma unroll
        for (int kk = 0; kk < 4; ++kk) {
            const float* wrow = &Ws[(k4 * 4 + kk) * 96 + tx * 12];
            float4 b0 = *(const float4*)(wrow);
            float4 b1 = *(const float4*)(wrow + 4);
            float4 b2 = *(const float4*)(wrow + 8);
            float av0 = (kk == 0) ? a0.x : (kk == 1) ? a0.y : (kk == 2) ? a0.z : a0.w;
            float av1 = (kk == 0) ? a1.x : (kk == 1) ? a1.y : (kk == 2) ? a1.z : a1.w;
            float av2 = (kk == 0) ? a2.x : (kk == 1) ? a2.y : (kk == 2) ? a2.z : a2.w;
            float av3 = (kk == 0) ? a3.x : (kk == 1) ? a3.y : (kk == 2) ? a3.z : a3.w;
            fma4(acc[0][0], av0, b0); fma4(acc[0][1], av0, b1); fma4(acc[0][2], av0, b2);
            fma4(acc[1][0], av1, b0); fma4(acc[1][1], av1, b1); fma4(acc[1][2], av1, b2);
            fma4(acc[2][0], av2, b0); fma4(acc[2][1], av2, b1); fma4(acc[2][2], av2, b2);
            fma4(acc[3][0], av3, b0); fma4(acc[3][1], av3, b1); fma4(acc[3][2], av3, b2);
        }
    }

    #pragma unroll
    for (int i = 0; i < 4; ++i) {
        if (!vr[i]) continue;
        int r = rbase + i;
        float dv = dinv[r];
        uint2* o = (uint2*)(g + (size_t)r * 96) + tx * 3;
        float4 t;
        t = acc[i][0]; o[0] = make_uint2(f2h(t.x * dv, t.y * dv), f2h(t.z * dv, t.w * dv));
        t = acc[i][1]; o[1] = make_uint2(f2h(t.x * dv, t.y * dv), f2h(t.z * dv, t.w * dv));
        t = acc[i][2]; o[2] = make_uint2(f2h(t.x * dv, t.y * dv), f2h(t.z * dv, t.w * dv));
    }
}

// ---- per-node fp16 gather + fused bias/relu/cfac weight + block partial of v ----
#define AGG_NODES 16
#define AGG_T (AGG_NODES * 24)
__launch_bounds__(AGG_T)
__global__ void k_agg(const uint2* __restrict__ g2, const int* __restrict__ col,
                      const int* __restrict__ rowptr, const float* __restrict__ dinv,
                      const float* __restrict__ cfac, const float* __restrict__ b1,
                      float* __restrict__ v_part, int n) {
    int tid = threadIdx.x;
    int nl = tid / 24;
    int ch = tid % 24;        // uint2 chunk of the 24-uint2 row (4 halves each)
    int d = blockIdx.x * AGG_NODES + nl;

    __shared__ float4 sh[AGG_NODES][24];

    float4 contrib = make_float4(0.f, 0.f, 0.f, 0.f);
    if (d < n) {
        float dd = dinv[d];
        int e0 = rowptr[d], e1 = rowptr[d + 1];
        float4 aA = make_float4(0.f, 0.f, 0.f, 0.f);
        float4 aB = make_float4(0.f, 0.f, 0.f, 0.f);
        int e = e0;
        for (; e + 4 <= e1; e += 4) {
            int s0 = col[e], s1 = col[e + 1], s2 = col[e + 2], s3 = col[e + 3];
            uint2 r0 = g2[(size_t)s0 * 24 + ch];
            uint2 r1 = g2[(size_t)s1 * 24 + ch];
            uint2 r2 = g2[(size_t)s2 * 24 + ch];
            uint2 r3 = g2[(size_t)s3 * 24 + ch];
            float2 f;
            f = h2f(r0.x); aA.x += f.x; aA.y += f.y;
            f = h2f(r0.y); aA.z += f.x; aA.w += f.y;
            f = h2f(r1.x); aB.x += f.x; aB.y += f.y;
            f = h2f(r1.y); aB.z += f.x; aB.w += f.y;
            f = h2f(r2.x); aA.x += f.x; aA.y += f.y;
            f = h2f(r2.y); aA.z += f.x; aA.w += f.y;
            f = h2f(r3.x); aB.x += f.x; aB.y += f.y;
            f = h2f(r3.y); aB.z += f.x; aB.w += f.y;
        }
        for (; e < e1; ++e) {
            uint2 r = g2[(size_t)col[e] * 24 + ch];
            float2 f;
            f = h2f(r.x); aA.x += f.x; aA.y += f.y;
            f = h2f(r.y); aA.z += f.x; aA.w += f.y;
        }
        uint2 rd = g2[(size_t)d * 24 + ch];   // analytic self-loop: g[d]*dinv[d]
        float2 fd0 = h2f(rd.x), fd1 = h2f(rd.y);
        float4 b1c = ((const float4*)b1)[ch];
        float cd = cfac[d];
        float hx = fmaxf(fmaf(dd, aA.x + aB.x + fd0.x, b1c.x), 0.f);
        float hy = fmaxf(fmaf(dd, aA.y + aB.y + fd0.y, b1c.y), 0.f);
        float hz = fmaxf(fmaf(dd, aA.z + aB.z + fd1.x, b1c.z), 0.f);
        float hw = fmaxf(fmaf(dd, aA.w + aB.w + fd1.y, b1c.w), 0.f);
        contrib = make_float4(cd * hx, cd * hy, cd * hz, cd * hw);
    }
    sh[nl][ch] = contrib;
    __syncthreads();
    #pragma unroll
    for (int off = 8; off >= 1; off >>= 1) {
        if (nl < off) {
            float4 a = sh[nl][ch];
            float4 b = sh[nl + off][ch];
            a.x += b.x; a.y += b.y; a.z += b.z; a.w += b.w;
            sh[nl][ch] = a;
        }
        __syncthreads();
    }
    if (tid < 24) {
        ((float4*)(v_part + (size_t)blockIdx.x * 96))[tid] = sh[0][tid];
    }
}

// ---- reduce v_part -> v[96] ----
__global__ void k_vred(const float* __restrict__ vp, float* __restrict__ v, int nb) {
    int j = blockIdx.x;
    float s = 0.f;
    for (int i = threadIdx.x; i < nb; i += 256) s += vp[(size_t)i * 96 + j];
    __shared__ float sh[256];
    sh[threadIdx.x] = s;
    __syncthreads();
    for (int off = 128; off; off >>= 1) {
        if (threadIdx.x < off) sh[threadIdx.x] += sh[threadIdx.x + off];
        __syncthreads();
    }
    if (threadIdx.x == 0) v[j] = sh[0];
}

// ---- mu = v@W_mu + N*b_mu ; logvar = v@W_lv + N*b_lv ----
__global__ void k_out(const float* __restrict__ v,
                      const float* __restrict__ Wmu, const float* __restrict__ bmu,
                      const float* __restrict__ Wlv, const float* __restrict__ blv,
                      float* __restrict__ out, float nN) {
    int tid = threadIdx.x;
    const float* W = (tid < 64) ? Wmu : Wlv;
    const float* b = (tid < 64) ? bmu : blv;
    int j = tid & 63;
    float s = 0.f;
    #pragma unroll
    for (int k = 0; k < 96; ++k) s = fmaf(v[k], W[k * 64 + j], s);
    out[tid] = s + nN * b[j];
}

extern "C" void kernel_launch(void* const* d_in, const int* in_sizes, int n_in,
                              void* d_out, int out_size, void* d_ws, size_t ws_size,
                              hipStream_t stream) {
    const float* x   = (const float*)d_in[0];
    const int*   ei  = (const int*)d_in[1];
    const float* W1  = (const float*)d_in[2];
    const float* b1  = (const float*)d_in[3];
    const float* Wmu = (const float*)d_in[4];
    const float* bmu = (const float*)d_in[5];
    const float* Wlv = (const float*)d_in[6];
    const float* blv = (const float*)d_in[7];
    float* out = (float*)d_out;

    const int N = in_sizes[0] / 128;   // 50000
    const int E = in_sizes[1] / 2;     // 800000
    const int* src = ei;
    const int* dst = ei + E;

    const int chunkE = (((E + NCHUNK - 1) / NCHUNK) + 3) & ~3;   // 25000
    const int sliceN = (N + NSLICE - 1) / NSLICE;                // 6250
    const int gN = (N + 255) / 256;                              // 196

    size_t off = 0;
    auto alloc = [&](size_t bytes) -> char* {
        off = (off + 255) & ~(size_t)255;
        char* p = (char*)d_ws + off;
        off += bytes;
        return p;
    };
    int*    partial  = (int*)alloc((size_t)NCHUNK * N * 4);   // counts->offs->rsum partials
    int*    rowptr   = (int*)alloc((size_t)(N + 1) * 4);
    int*    col      = (int*)alloc((size_t)E * 4);
    int*    deg      = (int*)alloc((size_t)N * 4);
    float*  dinv     = (float*)alloc((size_t)N * 4);
    float*  cfac     = (float*)alloc((size_t)N * 4);
    int*    blocksum = (int*)alloc((size_t)gN * 4);
    int*    blockoff = (int*)alloc((size_t)gN * 4);
    __half* g        = (__half*)alloc((size_t)N * 96 * 2);
    const int nAggBlocks = (N + AGG_NODES - 1) / AGG_NODES;
    float*  v_part   = (float*)alloc((size_t)nAggBlocks * 96 * 4);
    float*  v        = (float*)alloc(96 * 4);

    k_count<<<NCHUNK * NSLICE, SORT_T, 0, stream>>>(dst, partial, N, E, chunkE, sliceN);
    k_degdinv<<<gN, 256, 0, stream>>>(partial, deg, dinv, blocksum, N);
    k_bscan<<<1, 256, 0, stream>>>(blocksum, blockoff, rowptr + N, gN);
    k_offs<<<gN, 256, 0, stream>>>(partial, deg, blockoff, rowptr, N);
    k_place<<<NCHUNK * NSLICE, SORT_T, 0, stream>>>(src, dst, dinv, partial, col, N, E, chunkE, sliceN);
    k_gemm<<<(N + 127) / 128, 256, 0, stream>>>(x, W1, dinv, (const float*)partial, cfac, g, N);
    k_agg<<<nAggBlocks, AGG_T, 0, stream>>>((const uint2*)g, col, rowptr, dinv,
                                            cfac, b1, v_part, N);
    k_vred<<<96, 256, 0, stream>>>(v_part, v, nAggBlocks);
    k_out<<<1, 128, 0, stream>>>(v, Wmu, bmu, Wlv, blv, out, (float)N);
}

// Round 8
// 92.811 us; speedup vs baseline: 2.9293x; 1.0856x over previous
//
#include <hip/hip_runtime.h>
#include <hip/hip_fp16.h>

// GCN encoder, N=50000, E=800000, 128 -> 96 (relu) -> sum-pooled 64+64.
// Sum-pooled layer 2: out = (sum_u c[u]*h[u]) @ W + N*b,
//   c[u] = dinv[u]*(dinv[u] + rsum[u]),  rsum[u] = sum_{e: src=u} dinv[dst_e].
// Layer 1 with g[u] = (xW1)[u]*dinv[u]  (stored as fp8 e4m3, scaled x16):
//   h[d] = relu( (dinv[d]/16)*(sum_{e->d} g_s[src] + g_s[d]) + b1 )
// fp8 g: gather 77MB logical, 4.8MB table ~ one XCD L2. CSR build = counting
// sort (32 chunks x 8 slices, chunk-major XCD-colocated blocks), zero device
// atomics. 8 kernels (bscan folded into k_offs).

#define NTHREADS 256
#define NCHUNK 32
#define LOG_NCHUNK 5
#define NSLICE 8
#define SLICE_MAX 6272   // LDS hist capacity; N <= 8*6272
#define SORT_T 1024      // threads for count/place

typedef float v2f __attribute__((ext_vector_type(2)));

__device__ inline void fma4(float4& c, float a, const float4& b) {
    c.x = fmaf(a, b.x, c.x); c.y = fmaf(a, b.y, c.y);
    c.z = fmaf(a, b.z, c.z); c.w = fmaf(a, b.w, c.w);
}

// pack 4 floats -> 4 x fp8 e4m3 in one uint
__device__ inline unsigned pk_fp8(float a, float b, float c, float d) {
    int p = __builtin_amdgcn_cvt_pk_fp8_f32(a, b, 0, false);
    p = __builtin_amdgcn_cvt_pk_fp8_f32(c, d, p, true);
    return (unsigned)p;
}

// ---- K1: per-(chunk,slice) dst histogram via LDS ----
// c = bid & 31 (chunk-major) so a chunk's 8 slice-blocks share one XCD's L2.
__launch_bounds__(SORT_T)
__global__ void k_count(const int* __restrict__ dst, int* __restrict__ partial,
                        int N, int E, int chunkE, int sliceN) {
    int c = blockIdx.x & (NCHUNK - 1), s = blockIdx.x >> LOG_NCHUNK;
    int nbase = s * sliceN;
    __shared__ int hist[SLICE_MAX];
    for (int j = threadIdx.x; j < sliceN; j += SORT_T) hist[j] = 0;
    __syncthreads();
    int e0 = c * chunkE, e1 = min(e0 + chunkE, E);
    int ne = e1 - e0;
    const int4* d4 = (const int4*)(dst + e0);
    int n4 = ne >> 2;
    for (int i = threadIdx.x; i < n4; i += SORT_T) {
        int4 d = d4[i];
        unsigned q;
        q = (unsigned)(d.x - nbase); if (q < (unsigned)sliceN) atomicAdd(&hist[q], 1);
        q = (unsigned)(d.y - nbase); if (q < (unsigned)sliceN) atomicAdd(&hist[q], 1);
        q = (unsigned)(d.z - nbase); if (q < (unsigned)sliceN) atomicAdd(&hist[q], 1);
        q = (unsigned)(d.w - nbase); if (q < (unsigned)sliceN) atomicAdd(&hist[q], 1);
    }
    if (threadIdx.x < (ne & 3)) {
        int d = dst[e0 + (n4 << 2) + threadIdx.x];
        unsigned q = (unsigned)(d - nbase);
        if (q < (unsigned)sliceN) atomicAdd(&hist[q], 1);
    }
    __syncthreads();
    for (int j = threadIdx.x; j < sliceN; j += SORT_T) {
        int n = nbase + j;
        if (n < N) partial[(size_t)c * N + n] = hist[j];
    }
}

// ---- K2: deg = sum over chunks; dinv; per-block sum of deg ----
__launch_bounds__(256)
__global__ void k_degdinv(const int* __restrict__ partial, int* __restrict__ deg,
                          float* __restrict__ dinv, int* __restrict__ blocksum, int N) {
    int tid = threadIdx.x;
    int n = blockIdx.x * 256 + tid;
    int s = 0;
    if (n < N) {
        #pragma unroll
        for (int c = 0; c < NCHUNK; ++c) s += partial[(size_t)c * N + n];
        deg[n] = s;
        dinv[n] = rsqrtf((float)(s + 1));
    }
    __shared__ int sh[256];
    sh[tid] = s;
    __syncthreads();
    #pragma unroll
    for (int off = 128; off; off >>= 1) {
        if (tid < off) sh[tid] += sh[tid + off];
        __syncthreads();
    }
    if (tid == 0) blocksum[blockIdx.x] = sh[0];
}

// ---- K3: per-block scan of deg -> rowptr; partial counts -> abs offsets ----
// Block offset computed in-kernel: reduce blocksum[b < bid] (nb <= 256).
__launch_bounds__(256)
__global__ void k_offs(int* __restrict__ partial, const int* __restrict__ deg,
                       const int* __restrict__ blocksum, int* __restrict__ rowptr,
                       int N, int E, int nb) {
    int tid = threadIdx.x;
    __shared__ int sh[256];
    // 1) this block's global offset = sum of preceding block sums
    int bs = (tid < nb && tid < (int)blockIdx.x) ? blocksum[tid] : 0;
    sh[tid] = bs;
    __syncthreads();
    #pragma unroll
    for (int off = 128; off; off >>= 1) {
        if (tid < off) sh[tid] += sh[tid + off];
        __syncthreads();
    }
    int blockoff = sh[0];
    __syncthreads();
    // 2) intra-block exclusive scan of deg
    int n = blockIdx.x * 256 + tid;
    int v = (n < N) ? deg[n] : 0;
    sh[tid] = v;
    __syncthreads();
    for (int off = 1; off < 256; off <<= 1) {
        int t = (tid >= off) ? sh[tid - off] : 0;
        __syncthreads();
        sh[tid] += t;
        __syncthreads();
    }
    int run = blockoff + sh[tid] - v;   // exclusive prefix
    if (n < N) {
        rowptr[n] = run;
        #pragma unroll
        for (int c = 0; c < NCHUNK; ++c) {
            size_t ix = (size_t)c * N + n;
            int t = partial[ix];
            partial[ix] = run;
            run += t;
        }
    }
    if (blockIdx.x == 0 && tid == 0) rowptr[N] = E;
}

// ---- K4: place edges into col via LDS cursors; rsum partials into offs (dead) ----
__launch_bounds__(SORT_T)
__global__ void k_place(const int* __restrict__ src, const int* __restrict__ dst,
                        const float* __restrict__ dinv, int* __restrict__ offs,
                        int* __restrict__ col, int N, int E, int chunkE, int sliceN) {
    int c = blockIdx.x & (NCHUNK - 1), s = blockIdx.x >> LOG_NCHUNK;
    int nbase = s * sliceN;
    __shared__ int cur[SLICE_MAX];
    __shared__ float rs[SLICE_MAX];
    for (int j = threadIdx.x; j < sliceN; j += SORT_T) {
        int n = nbase + j;
        cur[j] = (n < N) ? offs[(size_t)c * N + n] : 0;
        rs[j] = 0.f;
    }
    __syncthreads();
    int e0 = c * chunkE, e1 = min(e0 + chunkE, E);
    int ne = e1 - e0;
    const int4* s4 = (const int4*)(src + e0);
    const int4* d4 = (const int4*)(dst + e0);
    int n4 = ne >> 2;
    for (int i = threadIdx.x; i < n4; i += SORT_T) {
        int4 sv = s4[i];
        int4 dv = d4[i];
        unsigned qd, qs;
        qd = (unsigned)(dv.x - nbase);
        if (qd < (unsigned)sliceN) { int p = atomicAdd(&cur[qd], 1); col[p] = sv.x; }
        qs = (unsigned)(sv.x - nbase);
        if (qs < (unsigned)sliceN) atomicAdd(&rs[qs], dinv[dv.x]);
        qd = (unsigned)(dv.y - nbase);
        if (qd < (unsigned)sliceN) { int p = atomicAdd(&cur[qd], 1); col[p] = sv.y; }
        qs = (unsigned)(sv.y - nbase);
        if (qs < (unsigned)sliceN) atomicAdd(&rs[qs], dinv[dv.y]);
        qd = (unsigned)(dv.z - nbase);
        if (qd < (unsigned)sliceN) { int p = atomicAdd(&cur[qd], 1); col[p] = sv.z; }
        qs = (unsigned)(sv.z - nbase);
        if (qs < (unsigned)sliceN) atomicAdd(&rs[qs], dinv[dv.z]);
        qd = (unsigned)(dv.w - nbase);
        if (qd < (unsigned)sliceN) { int p = atomicAdd(&cur[qd], 1); col[p] = sv.w; }
        qs = (unsigned)(sv.w - nbase);
        if (qs < (unsigned)sliceN) atomicAdd(&rs[qs], dinv[dv.w]);
    }
    if (threadIdx.x < (ne & 3)) {
        int e = e0 + (n4 << 2) + threadIdx.x;
        int sv = src[e], dv = dst[e];
        unsigned qd = (unsigned)(dv - nbase);
        if (qd < (unsigned)sliceN) { int p = atomicAdd(&cur[qd], 1); col[p] = sv; }
        unsigned qs = (unsigned)(sv - nbase);
        if (qs < (unsigned)sliceN) atomicAdd(&rs[qs], dinv[dv]);
    }
    __syncthreads();
    float* prs = (float*)offs;   // offs[c][this slice] dead after load -> reuse
    for (int j = threadIdx.x; j < sliceN; j += SORT_T) {
        int n = nbase + j;
        if (n < N) prs[(size_t)c * N + n] = rs[j];
    }
}

// ---- K5: g = fp8(16*(x @ W1)*dinv[row]); fused cfac = dinv*(dinv+rsum) ----
__launch_bounds__(256)
__global__ void k_gemm(const float* __restrict__ x, const float* __restrict__ W1,
                       const float* __restrict__ dinv, const float* __restrict__ prs,
                       float* __restrict__ cfac, unsigned* __restrict__ g, int n) {
    __shared__ float Ws[128 * 96];
    int tid = threadIdx.x;
    {
        const float4* wsrc = (const float4*)W1;
        float4* wdst = (float4*)Ws;
        #pragma unroll
        for (int i = 0; i < 12; ++i) wdst[tid + 256 * i] = wsrc[tid + 256 * i];
    }
    // fused rsum->cfac for this block's 128 rows (overlaps staging)
    {
        int r = blockIdx.x * 128 + tid;
        if (tid < 128 && r < n) {
            float s = 0.f;
            #pragma unroll
            for (int c = 0; c < NCHUNK; ++c) s += prs[(size_t)c * n + r];
            float dv = dinv[r];
            cfac[r] = dv * (dv + s);
        }
    }
    __syncthreads();

    int tx = tid & 7;          // 8 col groups of 12
    int ty = tid >> 3;         // 32 row quads
    int rbase = blockIdx.x * 128 + ty * 4;
    const float4* xp[4];
    bool vr[4];
    #pragma unroll
    for (int i = 0; i < 4; ++i) {
        int r = rbase + i;
        vr[i] = r < n;
        xp[i] = (const float4*)(x + (size_t)(vr[i] ? r : 0) * 128);
    }

    float4 acc[4][3];
    #pragma unroll
    for (int i = 0; i < 4; ++i)
        #pragma unroll
        for (int j = 0; j < 3; ++j) acc[i][j] = make_float4(0.f, 0.f, 0.f, 0.f);

    #pragma unroll 2
    for (int k4 = 0; k4 < 32; ++k4) {
        float4 a0 = xp[0][k4];
        float4 a1 = xp[1][k4];
        float4 a2 = xp[2][k4];
        float4 a3 = xp[3][k4];
        #pragma unroll
        for (int kk = 0; kk < 4; ++kk) {
            const float* wrow = &Ws[(k4 * 4 + kk) * 96 + tx * 12];
            float4 b0 = *(const float4*)(wrow);
            float4 b1 = *(const float4*)(wrow + 4);
            float4 b2 = *(const float4*)(wrow + 8);
            float av0 = (kk == 0) ? a0.x : (kk == 1) ? a0.y : (kk == 2) ? a0.z : a0.w;
            float av1 = (kk == 0) ? a1.x : (kk == 1) ? a1.y : (kk == 2) ? a1.z : a1.w;
            float av2 = (kk == 0) ? a2.x : (kk == 1) ? a2.y : (kk == 2) ? a2.z : a2.w;
            float av3 = (kk == 0) ? a3.x : (kk == 1) ? a3.y : (kk == 2) ? a3.z : a3.w;
            fma4(acc[0][0], av0, b0); fma4(acc[0][1], av0, b1); fma4(acc[0][2], av0, b2);
            fma4(acc[1][0], av1, b0); fma4(acc[1][1], av1, b1); fma4(acc[1][2], av1, b2);
            fma4(acc[2][0], av2, b0); fma4(acc[2][1], av2, b1); fma4(acc[2][2], av2, b2);
            fma4(acc[3][0], av3, b0); fma4(acc[3][1], av3, b1); fma4(acc[3][2], av3, b2);
        }
    }

    #pragma unroll
    for (int i = 0; i < 4; ++i) {
        if (!vr[i]) continue;
        int r = rbase + i;
        float dv = dinv[r] * 16.f;      // x16 scale for fp8 dynamic range
        unsigned* o = g + (size_t)r * 24 + tx * 3;
        float4 t;
        t = acc[i][0]; o[0] = pk_fp8(t.x * dv, t.y * dv, t.z * dv, t.w * dv);
        t = acc[i][1]; o[1] = pk_fp8(t.x * dv, t.y * dv, t.z * dv, t.w * dv);
        t = acc[i][2]; o[2] = pk_fp8(t.x * dv, t.y * dv, t.z * dv, t.w * dv);
    }
}

// ---- per-node fp8 gather + fused bias/relu/cfac weight + block partial of v ----
#define AGG_NODES 16
#define AGG_T (AGG_NODES * 24)
__launch_bounds__(AGG_T)
__global__ void k_agg(const unsigned* __restrict__ g1, const int* __restrict__ col,
                      const int* __restrict__ rowptr, const float* __restrict__ dinv,
                      const float* __restrict__ cfac, const float* __restrict__ b1,
                      float* __restrict__ v_part, int n) {
    int tid = threadIdx.x;
    int nl = tid / 24;
    int ch = tid % 24;        // uint chunk of the 24-uint row (4 fp8 each)
    int d = blockIdx.x * AGG_NODES + nl;

    __shared__ float4 sh[AGG_NODES][24];

    float4 contrib = make_float4(0.f, 0.f, 0.f, 0.f);
    if (d < n) {
        float dds = dinv[d] * 0.0625f;   // undo x16 storage scale
        int e0 = rowptr[d], e1 = rowptr[d + 1];
        float4 aA = make_float4(0.f, 0.f, 0.f, 0.f);
        float4 aB = make_float4(0.f, 0.f, 0.f, 0.f);
        int e = e0;
        for (; e + 4 <= e1; e += 4) {
            int s0 = col[e], s1 = col[e + 1], s2 = col[e + 2], s3 = col[e + 3];
            unsigned u0 = g1[(size_t)s0 * 24 + ch];
            unsigned u1 = g1[(size_t)s1 * 24 + ch];
            unsigned u2 = g1[(size_t)s2 * 24 + ch];
            unsigned u3 = g1[(size_t)s3 * 24 + ch];
            v2f f;
            f = __builtin_amdgcn_cvt_pk_f32_fp8(u0, false); aA.x += f.x; aA.y += f.y;
            f = __builtin_amdgcn_cvt_pk_f32_fp8(u0, true);  aA.z += f.x; aA.w += f.y;
            f = __builtin_amdgcn_cvt_pk_f32_fp8(u1, false); aB.x += f.x; aB.y += f.y;
            f = __builtin_amdgcn_cvt_pk_f32_fp8(u1, true);  aB.z += f.x; aB.w += f.y;
            f = __builtin_amdgcn_cvt_pk_f32_fp8(u2, false); aA.x += f.x; aA.y += f.y;
            f = __builtin_amdgcn_cvt_pk_f32_fp8(u2, true);  aA.z += f.x; aA.w += f.y;
            f = __builtin_amdgcn_cvt_pk_f32_fp8(u3, false); aB.x += f.x; aB.y += f.y;
            f = __builtin_amdgcn_cvt_pk_f32_fp8(u3, true);  aB.z += f.x; aB.w += f.y;
        }
        for (; e < e1; ++e) {
            unsigned u = g1[(size_t)col[e] * 24 + ch];
            v2f f;
            f = __builtin_amdgcn_cvt_pk_f32_fp8(u, false); aA.x += f.x; aA.y += f.y;
            f = __builtin_amdgcn_cvt_pk_f32_fp8(u, true);  aA.z += f.x; aA.w += f.y;
        }
        {   // analytic self-loop: g[d] joins the same sum
            unsigned u = g1[(size_t)d * 24 + ch];
            v2f f;
            f = __builtin_amdgcn_cvt_pk_f32_fp8(u, false); aA.x += f.x; aA.y += f.y;
            f = __builtin_amdgcn_cvt_pk_f32_fp8(u, true);  aA.z += f.x; aA.w += f.y;
        }
        float4 b1c = ((const float4*)b1)[ch];
        float cd = cfac[d];
        float hx = fmaxf(fmaf(dds, aA.x + aB.x, b1c.x), 0.f);
        float hy = fmaxf(fmaf(dds, aA.y + aB.y, b1c.y), 0.f);
        float hz = fmaxf(fmaf(dds, aA.z + aB.z, b1c.z), 0.f);
        float hw = fmaxf(fmaf(dds, aA.w + aB.w, b1c.w), 0.f);
        contrib = make_float4(cd * hx, cd * hy, cd * hz, cd * hw);
    }
    sh[nl][ch] = contrib;
    __syncthreads();
    #pragma unroll
    for (int off = 8; off >= 1; off >>= 1) {
        if (nl < off) {
            float4 a = sh[nl][ch];
            float4 b = sh[nl + off][ch];
            a.x += b.x; a.y += b.y; a.z += b.z; a.w += b.w;
            sh[nl][ch] = a;
        }
        __syncthreads();
    }
    if (tid < 24) {
        ((float4*)(v_part + (size_t)blockIdx.x * 96))[tid] = sh[0][tid];
    }
}

// ---- reduce v_part -> v[96] ----
__global__ void k_vred(const float* __restrict__ vp, float* __restrict__ v, int nb) {
    int j = blockIdx.x;
    float s = 0.f;
    for (int i = threadIdx.x; i < nb; i += 256) s += vp[(size_t)i * 96 + j];
    __shared__ float sh[256];
    sh[threadIdx.x] = s;
    __syncthreads();
    for (int off = 128; off; off >>= 1) {
        if (threadIdx.x < off) sh[threadIdx.x] += sh[threadIdx.x + off];
        __syncthreads();
    }
    if (threadIdx.x == 0) v[j] = sh[0];
}

// ---- mu = v@W_mu + N*b_mu ; logvar = v@W_lv + N*b_lv ----
__global__ void k_out(const float* __restrict__ v,
                      const float* __restrict__ Wmu, const float* __restrict__ bmu,
                      const float* __restrict__ Wlv, const float* __restrict__ blv,
                      float* __restrict__ out, float nN) {
    int tid = threadIdx.x;
    const float* W = (tid < 64) ? Wmu : Wlv;
    const float* b = (tid < 64) ? bmu : blv;
    int j = tid & 63;
    float s = 0.f;
    #pragma unroll
    for (int k = 0; k < 96; ++k) s = fmaf(v[k], W[k * 64 + j], s);
    out[tid] = s + nN * b[j];
}

extern "C" void kernel_launch(void* const* d_in, const int* in_sizes, int n_in,
                              void* d_out, int out_size, void* d_ws, size_t ws_size,
                              hipStream_t stream) {
    const float* x   = (const float*)d_in[0];
    const int*   ei  = (const int*)d_in[1];
    const float* W1  = (const float*)d_in[2];
    const float* b1  = (const float*)d_in[3];
    const float* Wmu = (const float*)d_in[4];
    const float* bmu = (const float*)d_in[5];
    const float* Wlv = (const float*)d_in[6];
    const float* blv = (const float*)d_in[7];
    float* out = (float*)d_out;

    const int N = in_sizes[0] / 128;   // 50000
    const int E = in_sizes[1] / 2;     // 800000
    const int* src = ei;
    const int* dst = ei + E;

    const int chunkE = (((E + NCHUNK - 1) / NCHUNK) + 3) & ~3;   // 25000
    const int sliceN = (N + NSLICE - 1) / NSLICE;                // 6250
    const int gN = (N + 255) / 256;                              // 196

    size_t off = 0;
    auto alloc = [&](size_t bytes) -> char* {
        off = (off + 255) & ~(size_t)255;
        char* p = (char*)d_ws + off;
        off += bytes;
        return p;
    };
    int*      partial  = (int*)alloc((size_t)NCHUNK * N * 4);   // counts->offs->rsum partials
    int*      rowptr   = (int*)alloc((size_t)(N + 1) * 4);
    int*      col      = (int*)alloc((size_t)E * 4);
    int*      deg      = (int*)alloc((size_t)N * 4);
    float*    dinv     = (float*)alloc((size_t)N * 4);
    float*    cfac     = (float*)alloc((size_t)N * 4);
    int*      blocksum = (int*)alloc((size_t)gN * 4);
    unsigned* g        = (unsigned*)alloc((size_t)N * 96);      // fp8 e4m3, 24 uints/row
    const int nAggBlocks = (N + AGG_NODES - 1) / AGG_NODES;
    float*    v_part   = (float*)alloc((size_t)nAggBlocks * 96 * 4);
    float*    v        = (float*)alloc(96 * 4);

    k_count<<<NCHUNK * NSLICE, SORT_T, 0, stream>>>(dst, partial, N, E, chunkE, sliceN);
    k_degdinv<<<gN, 256, 0, stream>>>(partial, deg, dinv, blocksum, N);
    k_offs<<<gN, 256, 0, stream>>>(partial, deg, blocksum, rowptr, N, E, gN);
    k_place<<<NCHUNK * NSLICE, SORT_T, 0, stream>>>(src, dst, dinv, partial, col, N, E, chunkE, sliceN);
    k_gemm<<<(N + 127) / 128, 256, 0, stream>>>(x, W1, dinv, (const float*)partial, cfac, g, N);
    k_agg<<<nAggBlocks, AGG_T, 0, stream>>>(g, col, rowptr, dinv, cfac, b1, v_part, N);
    k_vred<<<96, 256, 0, stream>>>(v_part, v, nAggBlocks);
    k_out<<<1, 128, 0, stream>>>(v, Wmu, bmu, Wlv, blv, out, (float)N);
}